// Round 9
// baseline (887.221 us; speedup 1.0000x reference)
//
#include <hip/hip_runtime.h>

// fTN_NNiso: batched PEPS amplitude, MI355X. TWO-PASS:
//  pass 1 gen_q : q[s][51200] = h_s @ W2 + b2 (bf16 into d_ws; chunked)
//  pass 2 tn_con: boundary-MPS sweep, G=2 samples/block, 256 threads:
//    waves 0-1 = phases (one wave per sample), waves 2-3 = staging.
// Round 4-8 spill lesson: acc[16] (64 VGPR) must be DEAD before p3.
// => full M2[4096]/sample in LDS (single-pass p3), with P aliased into
// M2[0:1024) (p1 reads P before the same wave's M2 writes; stage refills
// P only after the post-p3 barrier). No path exceeds ~120 live VGPRs.
// gen_q: h-stage via __ballot bitmasks (was 576 scalar W1 loads/thread);
// 256 samples/block over one W2 strip.
// peps strides (6,6,4,4,4,4,2): r:3072 c:512 l:128 rb:32 a:8 b:2 p:1

constexpr int   kNSites = 36;
constexpr int   kProj   = 51200;
constexpr float kEta    = 0.001f;
constexpr int   G       = 2;

__device__ __forceinline__ float4 f4fma(float s, float4 a, float4 c) {
    c.x = fmaf(s, a.x, c.x); c.y = fmaf(s, a.y, c.y);
    c.z = fmaf(s, a.z, c.z); c.w = fmaf(s, a.w, c.w);
    return c;
}
__device__ __forceinline__ unsigned short f2bf(float f) {
    union { float f; unsigned int u; } v; v.f = f;
    unsigned int r = v.u + 0x7FFFu + ((v.u >> 16) & 1u);  // RNE
    return (unsigned short)(r >> 16);
}
__device__ __forceinline__ float bf2f(unsigned int h) {
    union { unsigned int u; float f; } v; v.u = h << 16;
    return v.f;
}
// 8 bf16 (uint4) + 2 base float4 -> vec, two float4 LDS stores. ALL STATIC.
__device__ __forceinline__ void cvt8(const uint4 q, const float4 b0, const float4 b1,
                                     float* dst) {
    float4 o0, o1;
    o0.x = b0.x + kEta * bf2f(q.x & 0xffffu); o0.y = b0.y + kEta * bf2f(q.x >> 16);
    o0.z = b0.z + kEta * bf2f(q.y & 0xffffu); o0.w = b0.w + kEta * bf2f(q.y >> 16);
    o1.x = b1.x + kEta * bf2f(q.z & 0xffffu); o1.y = b1.y + kEta * bf2f(q.z >> 16);
    o1.z = b1.z + kEta * bf2f(q.w & 0xffffu); o1.w = b1.w + kEta * bf2f(q.w >> 16);
    *reinterpret_cast<float4*>(dst)     = o0;
    *reinterpret_cast<float4*>(dst + 4) = o1;
}

// ===================== PASS 1: q = h @ W2 + b2 (bf16) =====================
constexpr int HTS = 68;   // hT row stride (bank-spread, 16B-aligned)

__global__ __launch_bounds__(256)
void gen_q(const int* __restrict__ x,
           const float* __restrict__ W1,
           const float* __restrict__ b1,
           const float* __restrict__ W2,
           const float* __restrict__ b2,
           unsigned short* __restrict__ qout,
           int s0, int send)
{
    __shared__ float hT[64 * HTS];            // [k*68 + sl]
    __shared__ unsigned long long Bj[36];     // bit sl = x[sample sl][site j]
    const int tid  = threadIdx.x;
    const int wid  = tid >> 6;
    const int lane = tid & 63;
    const int sb0  = s0 + blockIdx.x * 256;
    const int ns   = blockIdx.y;              // 200 strips of 256 cols
    const int col  = ns * 256 + (tid & 63) * 4;
    const int sgrp = tid >> 6;                // 16-sample group within 64

    for (int sg = 0; sg < 4; ++sg) {
        const int sbase = sb0 + sg * 64;
        // ---- build Bj: wave wid handles j = wid*9 .. wid*9+8 ----
        {
            int sA = sbase + lane; if (sA >= send) sA = send - 1;
#pragma unroll
            for (int jj = 0; jj < 9; ++jj) {
                int j = wid * 9 + jj;
                unsigned long long m = __ballot(x[sA * kNSites + j] != 0);
                if (lane == 0) Bj[j] = m;
            }
        }
        __syncthreads();
        // ---- h for 64 samples: thread (k, slg) does 16 samples ----
        {
            const int k = tid & 63, slg = tid >> 6;
            float hacc[16];
            float bv = b1[k];
#pragma unroll
            for (int i = 0; i < 16; ++i) hacc[i] = bv;
#pragma unroll
            for (int j = 0; j < 36; ++j) {
                float w1 = W1[j * 64 + k];
                unsigned int bits = (unsigned int)((Bj[j] >> (slg * 16)) & 0xffffULL);
#pragma unroll
                for (int i = 0; i < 16; ++i)
                    hacc[i] += ((bits >> i) & 1u) ? w1 : 0.0f;
            }
#pragma unroll
            for (int i4 = 0; i4 < 4; ++i4) {
                float4 hv;
                hv.x = fmaxf(hacc[i4 * 4 + 0], 0.0f);
                hv.y = fmaxf(hacc[i4 * 4 + 1], 0.0f);
                hv.z = fmaxf(hacc[i4 * 4 + 2], 0.0f);
                hv.w = fmaxf(hacc[i4 * 4 + 3], 0.0f);
                *reinterpret_cast<float4*>(&hT[k * HTS + slg * 16 + i4 * 4]) = hv;
            }
        }
        __syncthreads();
        // ---- k-loop: 4 cols x 16 samples per thread ----
        float4 acc[16];
#pragma unroll
        for (int i = 0; i < 16; ++i) acc[i] = make_float4(0, 0, 0, 0);
        const float* wp = W2 + col;
#pragma unroll 8
        for (int k = 0; k < 64; ++k) {
            float4 w = *reinterpret_cast<const float4*>(wp + (size_t)k * kProj);
#pragma unroll
            for (int s4 = 0; s4 < 4; ++s4) {
                float4 hv = *reinterpret_cast<const float4*>(&hT[k * HTS + sgrp * 16 + s4 * 4]);
                acc[s4 * 4 + 0] = f4fma(hv.x, w, acc[s4 * 4 + 0]);
                acc[s4 * 4 + 1] = f4fma(hv.y, w, acc[s4 * 4 + 1]);
                acc[s4 * 4 + 2] = f4fma(hv.z, w, acc[s4 * 4 + 2]);
                acc[s4 * 4 + 3] = f4fma(hv.w, w, acc[s4 * 4 + 3]);
            }
        }
        float4 bb = *reinterpret_cast<const float4*>(b2 + col);
#pragma unroll
        for (int i = 0; i < 16; ++i) {
            int sA = sbase + sgrp * 16 + i;
            if (sA < send) {
                ushort4 uv;
                uv.x = f2bf(acc[i].x + bb.x); uv.y = f2bf(acc[i].y + bb.y);
                uv.z = f2bf(acc[i].z + bb.z); uv.w = f2bf(acc[i].w + bb.w);
                *reinterpret_cast<ushort4*>(qout + (size_t)(sA - s0) * kProj + col) = uv;
            }
        }
        __syncthreads();
    }
}

// ===================== PASS 2: contraction sweep =====================
// LDS layout (float offsets), G=2
constexpr int OFF_MS  = 0;         // [g][r-1][d][(u*4+l)^((d&7)<<2)]   2*4096
constexpr int OFF_MS0 = 8192;      // [g][d*4+l]                        2*64
constexpr int OFF_MS5 = 8320;      // [g][u*4+l]                        2*64
constexpr int OFF_Q   = 8448;      // [g][cq*68+ua]                     2*1088
constexpr int OFF_M2  = 10624;     // [g][ua*64 + (col^((ua>>2&7)<<2))] 2*4096; P aliased [0:1024)
constexpr int OFF_A2  = 18816;     // [g][lb*16+a*4+rb]                 2*256
constexpr int OFF_VB  = 19328;     // [g][16]                           32
constexpr int LTOT    = 19360;     // 77,440 B

__global__ __launch_bounds__(256, 2)
void tn_con(const int* __restrict__ x,
            const float* __restrict__ peps,
            const float* __restrict__ base_proj,
            const unsigned short* __restrict__ qc,
            float* __restrict__ out,
            int s0, int send)
{
    __shared__ __align__(16) float L[LTOT];
    __shared__ int xl[G * kNSites];

    const int tid   = threadIdx.x;
    const int wid   = tid >> 6;
    const int lane  = tid & 63;
    const int sBase = s0 + blockIdx.x * G;

    // ---- stage x ----
    if (tid < G * kNSites) {
        int g = tid / kNSites, ii = tid - g * kNSites;
        int s = sBase + g; if (s >= send) s = send - 1;
        xl[tid] = x[s * kNSites + ii];
    }
    for (int i = tid; i < 8448; i += 256) L[i] = 0.0f;  // Ms + Ms0 + Ms5
    __syncthreads();

    // ---- init boundary MPS from column 0 ----
    for (int idx = tid; idx < 1024; idx += 256) {
        int g = idx >> 9, rem = idx & 511;
        int rr = rem >> 6, u = (rem >> 4) & 3, d = (rem >> 2) & 3, l = rem & 3;
        if (rr >= 6) continue;
        int p = xl[g * kNSites + rr * 6];
        if (rr == 0) {
            if (u == 0) L[OFF_MS0 + g * 64 + d * 4 + l] = peps[l * 32 + d * 2 + p];
        } else if (rr == 5) {
            if (d == 0) L[OFF_MS5 + g * 64 + u * 4 + l] = peps[5 * 3072 + l * 32 + u * 8 + p];
        } else {
            L[OFF_MS + g * 4096 + (rr - 1) * 1024 + d * 64 + ((u * 4 + l) ^ ((d & 7) << 2))] =
                peps[rr * 3072 + l * 32 + u * 8 + d * 2 + p];
        }
    }
    __syncthreads();

    // ---- stage-wave context ----
    const int t   = tid - 128;            // 0..127 for wid>=2
    const int sg  = (t >> 6) & 1;
    const int k16 = t & 63;
    int sAbs = sBase + ((wid >= 2) ? sg : 0); if (sAbs >= send) sAbs = send - 1;
    const unsigned short* qcs = qc + (size_t)(sAbs - s0) * kProj;

    // ---- prologue: stage P(bond 0) + A2(site 0: c=1,r=0) ----
    if (wid >= 2) {
        const int go = k16 * 16;
        uint4 p0 = *reinterpret_cast<const uint4*>(qcs + go);
        uint4 p1 = *reinterpret_cast<const uint4*>(qcs + go + 8);
        float4 b0 = *reinterpret_cast<const float4*>(base_proj + go);
        float4 b1v = *reinterpret_cast<const float4*>(base_proj + go + 4);
        float4 b2v = *reinterpret_cast<const float4*>(base_proj + go + 8);
        float4 b3v = *reinterpret_cast<const float4*>(base_proj + go + 12);
        cvt8(p0, b0, b1v, &L[OFF_M2 + sg * 4096 + k16 * 16]);
        cvt8(p1, b2v, b3v, &L[OFF_M2 + sg * 4096 + k16 * 16 + 8]);
#pragma unroll
        for (int j = 0; j < 4; ++j) {
            int idx = t + j * 128;
            int g2 = idx >> 8, rest = idx & 255;
            int lb = rest >> 4, arb = rest & 15;
            int l = lb >> 2, b = lb & 3, a = arb >> 2, rb = arb & 3;
            float v = 0.0f;
            if (a < 1) {
                int p = xl[g2 * kNSites + 0 * 6 + 1];
                v = peps[1 * 512 + l * 128 + rb * 32 + a * 8 + b * 2 + p];
            }
            L[OFF_A2 + idx] = v;
        }
    }
    __syncthreads();

    // ---- site loop: s = (c-1)*6 + r ----
    for (int s = 0; s < 30; ++s) {
        const int r = s % 6;
        if (wid < 2) {
            // ================= PHASES (sample g = wid) =================
            const int g   = wid;
            const int Pb  = OFF_M2 + g * 4096;   // P alias
            const int M2b = OFF_M2 + g * 4096;
            const int Qb  = OFF_Q  + g * 1088;
            const int A2b = OFF_A2 + g * 256;

            if (r == 0) {
                const int cc = lane >> 2, rb = lane & 3;
                float mold0[16];
#pragma unroll
                for (int i = 0; i < 16; ++i) mold0[i] = 0.0f;
#pragma unroll
                for (int d = 0; d < 16; ++d) {
                    float4 ms = *reinterpret_cast<float4*>(&L[OFF_MS0 + g*64 + d*4]);
                    float msl[4] = {ms.x, ms.y, ms.z, ms.w};
#pragma unroll
                    for (int b = 0; b < 4; ++b) {
                        float pv = L[Pb + d*64 + b*16 + cc];
#pragma unroll
                        for (int l = 0; l < 4; ++l)
                            mold0[l*4+b] = fmaf(msl[l], pv, mold0[l*4+b]);
                    }
                }
                float o = 0.0f;
#pragma unroll
                for (int lb = 0; lb < 16; ++lb)
                    o = fmaf(mold0[lb], L[A2b + lb*16 + rb], o);
                L[OFF_MS0 + g*64 + cc*4 + rb] = o;
            } else if (r < 5) {
                const int u = lane & 15, ccq = lane >> 4;
                const int msr = OFF_MS + g*4096 + (r-1)*1024;
                // ---- b-outer fused p1+p2 (acc 64 + mold 16 live) ----
                float4 acc[16];
#pragma unroll
                for (int i = 0; i < 16; ++i) acc[i] = make_float4(0,0,0,0);
#pragma unroll
                for (int b = 0; b < 4; ++b) {
                    asm volatile("" ::: "memory");
                    float4 mold[4] = {make_float4(0,0,0,0), make_float4(0,0,0,0),
                                      make_float4(0,0,0,0), make_float4(0,0,0,0)};
#pragma unroll
                    for (int d = 0; d < 16; ++d) {
                        const int wsz = (d & 7) << 2;
                        float4 ms = *reinterpret_cast<float4*>(&L[msr + d*64 + ((u*4) ^ wsz)]);
                        float4 p  = *reinterpret_cast<float4*>(&L[Pb + d*64 + b*16 + ccq*4]);
                        mold[0] = f4fma(ms.x, p, mold[0]);
                        mold[1] = f4fma(ms.y, p, mold[1]);
                        mold[2] = f4fma(ms.z, p, mold[2]);
                        mold[3] = f4fma(ms.w, p, mold[3]);
                    }
#pragma unroll
                    for (int l = 0; l < 4; ++l) {
                        float ml[4] = {mold[l].x, mold[l].y, mold[l].z, mold[l].w};
#pragma unroll
                        for (int a = 0; a < 4; ++a) {
                            float4 av = *reinterpret_cast<float4*>(&L[A2b + (l*4+b)*16 + a*4]);
#pragma unroll
                            for (int cco = 0; cco < 4; ++cco)
                                acc[a*4+cco] = f4fma(ml[cco], av, acc[a*4+cco]);
                        }
                    }
                }
                // ---- write FULL M2 (acc dead after this) ----
                {
                    const int wsz = (u & 7) << 2;
#pragma unroll
                    for (int a = 0; a < 4; ++a)
#pragma unroll
                        for (int cco = 0; cco < 4; ++cco)
                            *reinterpret_cast<float4*>(
                                &L[M2b + (u*4+a)*64 + ((ccq*16 + cco*4) ^ wsz)]) = acc[a*4+cco];
                }
                // ---- single-pass p3: Ms' = Q @ M2 ----
                {
                    const int cq0 = (lane >> 3) * 2, colg = lane & 7;
                    float4 o0 = make_float4(0,0,0,0), o1 = o0, o2 = o0, o3 = o0;
#pragma unroll
                    for (int ua0 = 0; ua0 < 64; ua0 += 4) {
                        const int swq = ((ua0 >> 2) & 7) << 2;
                        float4 q0 = *reinterpret_cast<float4*>(&L[Qb + cq0*68 + ua0]);
                        float4 q1 = *reinterpret_cast<float4*>(&L[Qb + (cq0+1)*68 + ua0]);
                        const int colA = (colg*4) ^ swq;
                        const int colB = (32 + colg*4) ^ swq;
                        float4 mA0 = *reinterpret_cast<float4*>(&L[M2b + (ua0+0)*64 + colA]);
                        float4 mA1 = *reinterpret_cast<float4*>(&L[M2b + (ua0+1)*64 + colA]);
                        float4 mA2 = *reinterpret_cast<float4*>(&L[M2b + (ua0+2)*64 + colA]);
                        float4 mA3 = *reinterpret_cast<float4*>(&L[M2b + (ua0+3)*64 + colA]);
                        float4 mB0 = *reinterpret_cast<float4*>(&L[M2b + (ua0+0)*64 + colB]);
                        float4 mB1 = *reinterpret_cast<float4*>(&L[M2b + (ua0+1)*64 + colB]);
                        float4 mB2 = *reinterpret_cast<float4*>(&L[M2b + (ua0+2)*64 + colB]);
                        float4 mB3 = *reinterpret_cast<float4*>(&L[M2b + (ua0+3)*64 + colB]);
                        o0 = f4fma(q0.x, mA0, o0); o0 = f4fma(q0.y, mA1, o0);
                        o0 = f4fma(q0.z, mA2, o0); o0 = f4fma(q0.w, mA3, o0);
                        o1 = f4fma(q1.x, mA0, o1); o1 = f4fma(q1.y, mA1, o1);
                        o1 = f4fma(q1.z, mA2, o1); o1 = f4fma(q1.w, mA3, o1);
                        o2 = f4fma(q0.x, mB0, o2); o2 = f4fma(q0.y, mB1, o2);
                        o2 = f4fma(q0.z, mB2, o2); o2 = f4fma(q0.w, mB3, o2);
                        o3 = f4fma(q1.x, mB0, o3); o3 = f4fma(q1.y, mB1, o3);
                        o3 = f4fma(q1.z, mB2, o3); o3 = f4fma(q1.w, mB3, o3);
                    }
                    const int dnA = colg, dnB = colg + 8;
                    const int wsA = (dnA & 7) << 2, wsB = (dnB & 7) << 2;
                    *reinterpret_cast<float4*>(&L[msr + dnA*64 + ((cq0*4) ^ wsA)]) = o0;
                    *reinterpret_cast<float4*>(&L[msr + dnA*64 + (((cq0+1)*4) ^ wsA)]) = o1;
                    *reinterpret_cast<float4*>(&L[msr + dnB*64 + ((cq0*4) ^ wsB)]) = o2;
                    *reinterpret_cast<float4*>(&L[msr + dnB*64 + (((cq0+1)*4) ^ wsB)]) = o3;
                }
            } else { // r == 5
                {
                    const int u5 = lane >> 2, a5 = lane & 3;
                    float4 ms5 = *reinterpret_cast<float4*>(&L[OFF_MS5 + g*64 + u5*4]);
                    float m5l[4] = {ms5.x, ms5.y, ms5.z, ms5.w};
                    float4 o = make_float4(0,0,0,0);
#pragma unroll
                    for (int l = 0; l < 4; ++l) {
                        float4 av = *reinterpret_cast<float4*>(&L[A2b + (l*4)*16 + a5*4]);
                        o = f4fma(m5l[l], av, o);
                    }
                    *reinterpret_cast<float4*>(&L[M2b + lane*4]) = o;
                }
                {
                    const int cq = lane >> 2, rb = lane & 3;
                    float o = 0.0f;
#pragma unroll
                    for (int ua0 = 0; ua0 < 64; ua0 += 4) {
                        float4 q = *reinterpret_cast<float4*>(&L[Qb + cq*68 + ua0]);
                        o = fmaf(q.x, L[M2b + (ua0+0)*4 + rb], o);
                        o = fmaf(q.y, L[M2b + (ua0+1)*4 + rb], o);
                        o = fmaf(q.z, L[M2b + (ua0+2)*4 + rb], o);
                        o = fmaf(q.w, L[M2b + (ua0+3)*4 + rb], o);
                    }
                    L[OFF_MS5 + g*64 + cq*4 + rb] = o;
                }
            }
            __syncthreads();   // B: phases done (P/Q/A2/M2 free)
            __syncthreads();   // C: stage writes visible
        } else {
            // ================= STAGE (waves 2-3): site s+1 =================
            const int s1 = s + 1;
            const bool hasNext = (s1 < 30);
            const int r1 = s1 % 6, c1 = 1 + s1 / 6;
            const bool doP = hasNext && (r1 <= 4);
            const bool doQ = hasNext && (r1 >= 1);
            uint4 pq0 = make_uint4(0,0,0,0), pq1 = pq0, qq0 = pq0, qq1 = pq0;
            float4 pb0 = make_float4(0,0,0,0), pb1 = pb0, pb2 = pb0, pb3 = pb0;
            float4 qb0 = pb0, qb1 = pb0, qb2 = pb0, qb3 = pb0;
            float a2v[4] = {0, 0, 0, 0};
            if (doP) {
                const int go = (((c1 - 1) * 5 + r1) << 11) + k16 * 16;
                pq0 = *reinterpret_cast<const uint4*>(qcs + go);
                pq1 = *reinterpret_cast<const uint4*>(qcs + go + 8);
                pb0 = *reinterpret_cast<const float4*>(base_proj + go);
                pb1 = *reinterpret_cast<const float4*>(base_proj + go + 4);
                pb2 = *reinterpret_cast<const float4*>(base_proj + go + 8);
                pb3 = *reinterpret_cast<const float4*>(base_proj + go + 12);
            }
            if (doQ) {
                const int go = (((c1 - 1) * 5 + (r1 - 1)) << 11) + 1024 + k16 * 16;
                qq0 = *reinterpret_cast<const uint4*>(qcs + go);
                qq1 = *reinterpret_cast<const uint4*>(qcs + go + 8);
                qb0 = *reinterpret_cast<const float4*>(base_proj + go);
                qb1 = *reinterpret_cast<const float4*>(base_proj + go + 4);
                qb2 = *reinterpret_cast<const float4*>(base_proj + go + 8);
                qb3 = *reinterpret_cast<const float4*>(base_proj + go + 12);
            }
            if (hasNext) {
                const int adim = (r1 == 0) ? 1 : 4;
                const int bdim = (r1 == 5) ? 1 : 4;
                const int rdim = (c1 == 5) ? 1 : 4;
#pragma unroll
                for (int j = 0; j < 4; ++j) {
                    int idx = t + j * 128;
                    int g2 = idx >> 8, rest = idx & 255;
                    int lb = rest >> 4, arb = rest & 15;
                    int l = lb >> 2, b = lb & 3, a = arb >> 2, rb = arb & 3;
                    float v = 0.0f;
                    if (a < adim && b < bdim && rb < rdim) {
                        int p = xl[g2 * kNSites + r1 * 6 + c1];
                        v = peps[r1 * 3072 + c1 * 512 + l * 128 + rb * 32 + a * 8 + b * 2 + p];
                    }
                    a2v[j] = v;
                }
            }
            __syncthreads();   // B: phases done -> buffers writable
            if (doP) {
                cvt8(pq0, pb0, pb1, &L[OFF_M2 + sg * 4096 + k16 * 16]);
                cvt8(pq1, pb2, pb3, &L[OFF_M2 + sg * 4096 + k16 * 16 + 8]);
            }
            if (doQ) {
                const int dst = OFF_Q + sg * 1088 + (k16 >> 2) * 68 + (k16 & 3) * 16;
                cvt8(qq0, qb0, qb1, &L[dst]);
                cvt8(qq1, qb2, qb3, &L[dst + 8]);
            }
            if (hasNext) {
#pragma unroll
                for (int j = 0; j < 4; ++j)
                    L[OFF_A2 + t + j * 128] = a2v[j];
            }
            __syncthreads();   // C
        }
    }

    // ---- final chain contraction (rb = 0 after c=5) ----
    if (wid < 2) {
        const int g = wid;
        if (lane < 16) L[OFF_VB + g*16 + lane] = L[OFF_MS0 + g*64 + lane*4];
        for (int rr = 1; rr < 5; ++rr) {
            float a = 0.0f;
            if (lane < 16) {
#pragma unroll
                for (int u = 0; u < 16; ++u)
                    a = fmaf(L[OFF_VB + g*16 + u],
                             L[OFF_MS + g*4096 + (rr-1)*1024 + lane*64 + ((u*4) ^ ((lane&7)<<2))], a);
            }
            if (lane < 16) L[OFF_VB + g*16 + lane] = a;
        }
        if (lane == 0 && sBase + g < send) {
            float a = 0.0f;
#pragma unroll
            for (int u = 0; u < 16; ++u)
                a = fmaf(L[OFF_VB + g*16 + u], L[OFF_MS5 + g*64 + u*4], a);
            out[sBase + g] = a;
        }
    }
}

extern "C" void kernel_launch(void* const* d_in, const int* in_sizes, int n_in,
                              void* d_out, int out_size, void* d_ws, size_t ws_size,
                              hipStream_t stream) {
    const int*   x         = (const int*)d_in[0];
    const float* peps      = (const float*)d_in[1];
    const float* base_proj = (const float*)d_in[2];
    const float* W1        = (const float*)d_in[3];
    const float* b1        = (const float*)d_in[4];
    const float* W2        = (const float*)d_in[5];
    const float* b2        = (const float*)d_in[6];
    float*       out       = (float*)d_out;

    const int batch = in_sizes[0] / kNSites;
    const size_t perS = (size_t)kProj * 2;  // bf16 bytes per sample
    int cs = (int)(ws_size / perS);
    if (cs > batch) cs = batch;
    cs &= ~3;
    if (cs < 4) cs = 4;  // requires ws_size >= 409600 B

    for (int s0 = 0; s0 < batch; s0 += cs) {
        int send = s0 + cs; if (send > batch) send = batch;
        int n = send - s0;
        dim3 g1((n + 255) / 256, 200);
        hipLaunchKernelGGL(gen_q, g1, dim3(256), 0, stream,
                           x, W1, b1, W2, b2, (unsigned short*)d_ws, s0, send);
        hipLaunchKernelGGL(tn_con, dim3((n + G - 1) / G), dim3(256), 0, stream,
                           x, peps, base_proj, (const unsigned short*)d_ws, out, s0, send);
    }
}

// Round 10
// 471.484 us; speedup vs baseline: 1.8818x; 1.8818x over previous
//
#include <hip/hip_runtime.h>

// fTN_NNiso: batched PEPS amplitude, MI355X. TWO-PASS:
//  pass 1 gen_q : q[s][51200] = h_s @ W2 + b2 (bf16 into d_ws; chunked)
//  pass 2 tn_con: boundary-MPS sweep, G=2 samples/block, 256 threads.
//    ALL 256 threads cooperate on ONE sample's phases (serial over g),
//    round-3 style: Mold kept in shared LDS, per-thread acc <= 4 float4.
//    Rounds 4-9 lesson: acc[16]-float4 fused phases spill at VGPR=128
//    no matter how they're arranged; round-3 style (VGPR 88) never did.
//    p2/p3 split into column halves (M2H 2048) so LDS = 77.8KB -> 2 blk/CU.
//    Staging inline (T14): issue next-site loads at site top (regs ~26),
//    write LDS after last phase barrier. Single-buffered P/Q/A2.
// peps strides (6,6,4,4,4,4,2): r:3072 c:512 l:128 rb:32 a:8 b:2 p:1

constexpr int   kNSites = 36;
constexpr int   kProj   = 51200;
constexpr float kEta    = 0.001f;
constexpr int   G       = 2;

__device__ __forceinline__ float4 f4fma(float s, float4 a, float4 c) {
    c.x = fmaf(s, a.x, c.x); c.y = fmaf(s, a.y, c.y);
    c.z = fmaf(s, a.z, c.z); c.w = fmaf(s, a.w, c.w);
    return c;
}
__device__ __forceinline__ unsigned short f2bf(float f) {
    union { float f; unsigned int u; } v; v.f = f;
    unsigned int r = v.u + 0x7FFFu + ((v.u >> 16) & 1u);  // RNE
    return (unsigned short)(r >> 16);
}
__device__ __forceinline__ float bf2f(unsigned int h) {
    union { unsigned int u; float f; } v; v.u = h << 16;
    return v.f;
}
// 8 bf16 (uint4) + 2 base float4 -> vec, two float4 LDS stores. ALL STATIC.
__device__ __forceinline__ void cvt8(const uint4 q, const float4 b0, const float4 b1,
                                     float* dst) {
    float4 o0, o1;
    o0.x = b0.x + kEta * bf2f(q.x & 0xffffu); o0.y = b0.y + kEta * bf2f(q.x >> 16);
    o0.z = b0.z + kEta * bf2f(q.y & 0xffffu); o0.w = b0.w + kEta * bf2f(q.y >> 16);
    o1.x = b1.x + kEta * bf2f(q.z & 0xffffu); o1.y = b1.y + kEta * bf2f(q.z >> 16);
    o1.z = b1.z + kEta * bf2f(q.w & 0xffffu); o1.w = b1.w + kEta * bf2f(q.w >> 16);
    *reinterpret_cast<float4*>(dst)     = o0;
    *reinterpret_cast<float4*>(dst + 4) = o1;
}

// ===================== PASS 1: q = h @ W2 + b2 (bf16) =====================
constexpr int HTS = 68;   // hT row stride (bank-spread, 16B-aligned)

__global__ __launch_bounds__(256)
void gen_q(const int* __restrict__ x,
           const float* __restrict__ W1,
           const float* __restrict__ b1,
           const float* __restrict__ W2,
           const float* __restrict__ b2,
           unsigned short* __restrict__ qout,
           int s0, int send)
{
    __shared__ float hT[64 * HTS];            // [k*68 + sl]
    __shared__ unsigned long long Bj[36];     // bit sl = x[sample sl][site j]
    const int tid  = threadIdx.x;
    const int wid  = tid >> 6;
    const int lane = tid & 63;
    const int sb0  = s0 + blockIdx.x * 256;
    const int ns   = blockIdx.y;              // 200 strips of 256 cols
    const int col  = ns * 256 + (tid & 63) * 4;
    const int sgrp = tid >> 6;                // 16-sample group within 64

    for (int sg = 0; sg < 4; ++sg) {
        const int sbase = sb0 + sg * 64;
        {
            int sA = sbase + lane; if (sA >= send) sA = send - 1;
#pragma unroll
            for (int jj = 0; jj < 9; ++jj) {
                int j = wid * 9 + jj;
                unsigned long long m = __ballot(x[sA * kNSites + j] != 0);
                if (lane == 0) Bj[j] = m;
            }
        }
        __syncthreads();
        {
            const int k = tid & 63, slg = tid >> 6;
            float hacc[16];
            float bv = b1[k];
#pragma unroll
            for (int i = 0; i < 16; ++i) hacc[i] = bv;
#pragma unroll
            for (int j = 0; j < 36; ++j) {
                float w1 = W1[j * 64 + k];
                unsigned int bits = (unsigned int)((Bj[j] >> (slg * 16)) & 0xffffULL);
#pragma unroll
                for (int i = 0; i < 16; ++i)
                    hacc[i] += ((bits >> i) & 1u) ? w1 : 0.0f;
            }
#pragma unroll
            for (int i4 = 0; i4 < 4; ++i4) {
                float4 hv;
                hv.x = fmaxf(hacc[i4 * 4 + 0], 0.0f);
                hv.y = fmaxf(hacc[i4 * 4 + 1], 0.0f);
                hv.z = fmaxf(hacc[i4 * 4 + 2], 0.0f);
                hv.w = fmaxf(hacc[i4 * 4 + 3], 0.0f);
                *reinterpret_cast<float4*>(&hT[k * HTS + slg * 16 + i4 * 4]) = hv;
            }
        }
        __syncthreads();
        float4 acc[16];
#pragma unroll
        for (int i = 0; i < 16; ++i) acc[i] = make_float4(0, 0, 0, 0);
        const float* wp = W2 + col;
#pragma unroll 8
        for (int k = 0; k < 64; ++k) {
            float4 w = *reinterpret_cast<const float4*>(wp + (size_t)k * kProj);
#pragma unroll
            for (int s4 = 0; s4 < 4; ++s4) {
                float4 hv = *reinterpret_cast<const float4*>(&hT[k * HTS + sgrp * 16 + s4 * 4]);
                acc[s4 * 4 + 0] = f4fma(hv.x, w, acc[s4 * 4 + 0]);
                acc[s4 * 4 + 1] = f4fma(hv.y, w, acc[s4 * 4 + 1]);
                acc[s4 * 4 + 2] = f4fma(hv.z, w, acc[s4 * 4 + 2]);
                acc[s4 * 4 + 3] = f4fma(hv.w, w, acc[s4 * 4 + 3]);
            }
        }
        float4 bb = *reinterpret_cast<const float4*>(b2 + col);
#pragma unroll
        for (int i = 0; i < 16; ++i) {
            int sA = sbase + sgrp * 16 + i;
            if (sA < send) {
                ushort4 uv;
                uv.x = f2bf(acc[i].x + bb.x); uv.y = f2bf(acc[i].y + bb.y);
                uv.z = f2bf(acc[i].z + bb.z); uv.w = f2bf(acc[i].w + bb.w);
                *reinterpret_cast<ushort4*>(qout + (size_t)(sA - s0) * kProj + col) = uv;
            }
        }
        __syncthreads();
    }
}

// ===================== PASS 2: contraction sweep =====================
// LDS (float offsets), G=2. Mold/M2H shared across samples (serial over g).
constexpr int OFF_MS   = 0;       // [g][r-1][d][(u*4+l)^((d&7)<<2)]     2*4096
constexpr int OFF_MS0  = 8192;    // [g][d*4+l]                          2*64
constexpr int OFF_MS5  = 8320;    // [g][u*4+l]                          2*64
constexpr int OFF_P    = 8448;    // [g][(d*4+b)*16+cc]                  2*1024
constexpr int OFF_Q    = 10496;   // [g][cq*68+ua]                       2*1088
constexpr int OFF_MOLD = 12672;   // [(u*16+lb)*16 + (cc^((u&3)<<2))]    4096 (shared)
constexpr int OFF_M2H  = 16768;   // [ua*32 + (colh^((ua&7)<<2))]        2048 (shared)
constexpr int OFF_A2   = 18816;   // [g][lb*16+a*4+rb]                   2*256
constexpr int OFF_VB   = 19328;   // [g][16]                             32
constexpr int LTOT     = 19360;   // 77,440 B

__global__ __launch_bounds__(256, 2)
void tn_con(const int* __restrict__ x,
            const float* __restrict__ peps,
            const float* __restrict__ base_proj,
            const unsigned short* __restrict__ qc,
            float* __restrict__ out,
            int s0, int send)
{
    __shared__ __align__(16) float L[LTOT];
    __shared__ int xl[G * kNSites];

    const int tid   = threadIdx.x;
    const int wid   = tid >> 6;
    const int lane  = tid & 63;
    const int sBase = s0 + blockIdx.x * G;

    // ---- stage x ----
    if (tid < G * kNSites) {
        int g = tid / kNSites, ii = tid - g * kNSites;
        int s = sBase + g; if (s >= send) s = send - 1;
        xl[tid] = x[s * kNSites + ii];
    }
    for (int i = tid; i < 8448; i += 256) L[i] = 0.0f;  // Ms + Ms0 + Ms5
    __syncthreads();

    // ---- init boundary MPS from column 0 ----
    for (int idx = tid; idx < 1024; idx += 256) {
        int g = idx >> 9, rem = idx & 511;
        int rr = rem >> 6, u = (rem >> 4) & 3, d = (rem >> 2) & 3, l = rem & 3;
        if (rr >= 6) continue;
        int p = xl[g * kNSites + rr * 6];
        if (rr == 0) {
            if (u == 0) L[OFF_MS0 + g * 64 + d * 4 + l] = peps[l * 32 + d * 2 + p];
        } else if (rr == 5) {
            if (d == 0) L[OFF_MS5 + g * 64 + u * 4 + l] = peps[5 * 3072 + l * 32 + u * 8 + p];
        } else {
            L[OFF_MS + g * 4096 + (rr - 1) * 1024 + d * 64 + ((u * 4 + l) ^ ((d & 7) << 2))] =
                peps[rr * 3072 + l * 32 + u * 8 + d * 2 + p];
        }
    }

    // per-thread staging identity: sample sgp, 8-elem chunk k8
    const int sgp = tid >> 7;
    const int k8  = (tid & 127) * 8;
    int sAbs = sBase + sgp; if (sAbs >= send) sAbs = send - 1;
    const unsigned short* qcs = qc + (size_t)(sAbs - s0) * kProj;

    // ---- prologue: stage P(bond 0) + A2(site 0: c=1,r=0) ----
    {
        uint4 pq = *reinterpret_cast<const uint4*>(qcs + k8);
        float4 b0 = *reinterpret_cast<const float4*>(base_proj + k8);
        float4 b1v = *reinterpret_cast<const float4*>(base_proj + k8 + 4);
        cvt8(pq, b0, b1v, &L[OFF_P + sgp * 1024 + k8]);
#pragma unroll
        for (int e = 0; e < 2; ++e) {
            int idx = tid * 2 + e;
            int g2 = idx >> 8, rest = idx & 255;
            int lb = rest >> 4, arb = rest & 15;
            int l = lb >> 2, b = lb & 3, a = arb >> 2, rb = arb & 3;
            float v = 0.0f;
            if (a < 1) {
                int p = xl[g2 * kNSites + 0 * 6 + 1];
                v = peps[1 * 512 + l * 128 + rb * 32 + a * 8 + b * 2 + p];
            }
            L[OFF_A2 + idx] = v;
        }
    }
    __syncthreads();

    // ---- site loop: s = (c-1)*6 + r ----
    for (int s = 0; s < 30; ++s) {
        const int r = s % 6;

        // ===== A: issue next-site loads into registers =====
        const int s1 = s + 1;
        const bool hasNext = (s1 < 30);
        const int r1 = s1 % 6, c1 = 1 + s1 / 6;
        const bool doP = hasNext && (r1 <= 4);
        const bool doQ = hasNext && (r1 >= 1);
        uint4 pq = make_uint4(0, 0, 0, 0), qq = pq;
        float4 pb0 = make_float4(0, 0, 0, 0), pb1 = pb0, qb0 = pb0, qb1 = pb0;
        float a2v0 = 0.0f, a2v1 = 0.0f;
        if (doP) {
            const int go = ((c1 - 1) * 5 + r1) * 2048 + k8;
            pq  = *reinterpret_cast<const uint4*>(qcs + go);
            pb0 = *reinterpret_cast<const float4*>(base_proj + go);
            pb1 = *reinterpret_cast<const float4*>(base_proj + go + 4);
        }
        if (doQ) {
            const int go = ((c1 - 1) * 5 + (r1 - 1)) * 2048 + 1024 + k8;
            qq  = *reinterpret_cast<const uint4*>(qcs + go);
            qb0 = *reinterpret_cast<const float4*>(base_proj + go);
            qb1 = *reinterpret_cast<const float4*>(base_proj + go + 4);
        }
        if (hasNext) {
            const int adim = (r1 == 0) ? 1 : 4;
            const int bdim = (r1 == 5) ? 1 : 4;
            const int rdim = (c1 == 5) ? 1 : 4;
#pragma unroll
            for (int e = 0; e < 2; ++e) {
                int idx = tid * 2 + e;
                int g2 = idx >> 8, rest = idx & 255;
                int lb = rest >> 4, arb = rest & 15;
                int l = lb >> 2, b = lb & 3, a = arb >> 2, rb = arb & 3;
                float v = 0.0f;
                if (a < adim && b < bdim && rb < rdim) {
                    int p = xl[g2 * kNSites + r1 * 6 + c1];
                    v = peps[r1 * 3072 + c1 * 512 + l * 128 + rb * 32 + a * 8 + b * 2 + p];
                }
                if (e == 0) a2v0 = v; else a2v1 = v;
            }
        }

        // ===== B: phases =====
        if (r == 0) {
            if (wid < 2) {   // wave g = wid, one sample each; tiny phase
                const int g = wid;
                const int cc = lane >> 2, rb = lane & 3;
                float mold0[16];
#pragma unroll
                for (int i = 0; i < 16; ++i) mold0[i] = 0.0f;
#pragma unroll
                for (int d = 0; d < 16; ++d) {
                    float4 ms = *reinterpret_cast<float4*>(&L[OFF_MS0 + g * 64 + d * 4]);
                    float msl[4] = {ms.x, ms.y, ms.z, ms.w};
#pragma unroll
                    for (int b = 0; b < 4; ++b) {
                        float pv = L[OFF_P + g * 1024 + (d * 4 + b) * 16 + cc];
#pragma unroll
                        for (int l = 0; l < 4; ++l)
                            mold0[l * 4 + b] = fmaf(msl[l], pv, mold0[l * 4 + b]);
                    }
                }
                float o = 0.0f;
#pragma unroll
                for (int lb = 0; lb < 16; ++lb)
                    o = fmaf(mold0[lb], L[OFF_A2 + g * 256 + lb * 16 + rb], o);
                L[OFF_MS0 + g * 64 + cc * 4 + rb] = o;
            }
            __syncthreads();
        } else if (r < 5) {
            for (int g = 0; g < 2; ++g) {
                const int msr = OFF_MS + g * 4096 + (r - 1) * 1024;
                // ---- p1 (all 256 threads): Mold[u][lb][cc] ----
                {
                    const int u = tid >> 4, lb = tid & 15;
                    const int l = lb >> 2, b = lb & 3;
                    const int pxr = (u & 3) << 2;
                    float4 a0 = make_float4(0, 0, 0, 0), a1 = a0, a2 = a0, a3 = a0;
#pragma unroll
                    for (int d = 0; d < 16; ++d) {
                        float ms = L[msr + d * 64 + ((u * 4 + l) ^ ((d & 7) << 2))];
                        const int pb = OFF_P + g * 1024 + (d * 4 + b) * 16;
                        float4 p0 = *reinterpret_cast<float4*>(&L[pb + 0]);
                        float4 p1 = *reinterpret_cast<float4*>(&L[pb + 4]);
                        float4 p2 = *reinterpret_cast<float4*>(&L[pb + 8]);
                        float4 p3 = *reinterpret_cast<float4*>(&L[pb + 12]);
                        a0 = f4fma(ms, p0, a0); a1 = f4fma(ms, p1, a1);
                        a2 = f4fma(ms, p2, a2); a3 = f4fma(ms, p3, a3);
                    }
                    const int mrow = OFF_MOLD + (u * 16 + lb) * 16;
                    *reinterpret_cast<float4*>(&L[mrow + (0  ^ pxr)]) = a0;
                    *reinterpret_cast<float4*>(&L[mrow + (4  ^ pxr)]) = a1;
                    *reinterpret_cast<float4*>(&L[mrow + (8  ^ pxr)]) = a2;
                    *reinterpret_cast<float4*>(&L[mrow + (12 ^ pxr)]) = a3;
                }
                __syncthreads();
                // ---- p2/p3 in column halves ----
#pragma unroll
                for (int h = 0; h < 2; ++h) {
                    // p2 half: M2H[ua][colh] = sum_lb Mold[u][lb][cc]*A2[lb][a,rb]
                    {
                        const int ua = tid >> 2, colq = tid & 3;
                        const int u2 = ua >> 2, a2i = ua & 3;
                        const int pxr = (u2 & 3) << 2;
                        const int cc0 = h * 8 + colq * 2;
                        float4 acc0 = make_float4(0, 0, 0, 0), acc1 = acc0;
#pragma unroll
                        for (int lb = 0; lb < 16; ++lb) {
                            float2 mo = *reinterpret_cast<float2*>(
                                &L[OFF_MOLD + (u2 * 16 + lb) * 16 + (cc0 ^ pxr)]);
                            float4 av = *reinterpret_cast<float4*>(
                                &L[OFF_A2 + g * 256 + lb * 16 + a2i * 4]);
                            acc0 = f4fma(mo.x, av, acc0);
                            acc1 = f4fma(mo.y, av, acc1);
                        }
                        const int m2x = (ua & 7) << 2;
                        *reinterpret_cast<float4*>(
                            &L[OFF_M2H + ua * 32 + (((colq * 2 + 0) * 4) ^ m2x)]) = acc0;
                        *reinterpret_cast<float4*>(
                            &L[OFF_M2H + ua * 32 + (((colq * 2 + 1) * 4) ^ m2x)]) = acc1;
                    }
                    __syncthreads();
                    // p3 half: Ms'[cq][dn][rb] = sum_ua Q[cq][ua]*M2H[ua][colh]
                    {
                        const int cq = tid >> 4, cp = tid & 15;
                        const int qb = OFF_Q + g * 1088 + cq * 68;
                        float ox = 0.0f, oy = 0.0f;
#pragma unroll
                        for (int ua0 = 0; ua0 < 64; ua0 += 4) {
                            float4 q = *reinterpret_cast<float4*>(&L[qb + ua0]);
                            float2 m0 = *reinterpret_cast<float2*>(
                                &L[OFF_M2H + (ua0 + 0) * 32 + ((cp * 2) ^ (((ua0 + 0) & 7) << 2))]);
                            float2 m1 = *reinterpret_cast<float2*>(
                                &L[OFF_M2H + (ua0 + 1) * 32 + ((cp * 2) ^ (((ua0 + 1) & 7) << 2))]);
                            float2 m2 = *reinterpret_cast<float2*>(
                                &L[OFF_M2H + (ua0 + 2) * 32 + ((cp * 2) ^ (((ua0 + 2) & 7) << 2))]);
                            float2 m3 = *reinterpret_cast<float2*>(
                                &L[OFF_M2H + (ua0 + 3) * 32 + ((cp * 2) ^ (((ua0 + 3) & 7) << 2))]);
                            ox = fmaf(q.x, m0.x, ox); oy = fmaf(q.x, m0.y, oy);
                            ox = fmaf(q.y, m1.x, ox); oy = fmaf(q.y, m1.y, oy);
                            ox = fmaf(q.z, m2.x, ox); oy = fmaf(q.z, m2.y, oy);
                            ox = fmaf(q.w, m3.x, ox); oy = fmaf(q.w, m3.y, oy);
                        }
                        const int dn = h * 8 + (cp >> 1);
                        const int rb0 = (cp & 1) * 2;
                        float2 o2; o2.x = ox; o2.y = oy;
                        *reinterpret_cast<float2*>(
                            &L[msr + dn * 64 + ((cq * 4 + rb0) ^ ((dn & 7) << 2))]) = o2;
                    }
                    __syncthreads();
                }
            }
        } else { // r == 5
            if (wid < 2) {
                const int g = wid;
                const int A2b = OFF_A2 + g * 256;
                const int M2b = OFF_M2H + g * 256;
                {
                    const int u5 = lane >> 2, a5 = lane & 3;
                    float4 ms5 = *reinterpret_cast<float4*>(&L[OFF_MS5 + g * 64 + u5 * 4]);
                    float4 o = make_float4(0, 0, 0, 0);
                    o = f4fma(ms5.x, *reinterpret_cast<float4*>(&L[A2b + 0 * 16 + a5 * 4]), o);
                    o = f4fma(ms5.y, *reinterpret_cast<float4*>(&L[A2b + 4 * 16 + a5 * 4]), o);
                    o = f4fma(ms5.z, *reinterpret_cast<float4*>(&L[A2b + 8 * 16 + a5 * 4]), o);
                    o = f4fma(ms5.w, *reinterpret_cast<float4*>(&L[A2b + 12 * 16 + a5 * 4]), o);
                    *reinterpret_cast<float4*>(&L[M2b + lane * 4]) = o;
                }
                {
                    const int cq = lane >> 2, rb = lane & 3;
                    const int qb = OFF_Q + g * 1088 + cq * 68;
                    float o = 0.0f;
#pragma unroll
                    for (int ua0 = 0; ua0 < 64; ua0 += 4) {
                        float4 q = *reinterpret_cast<float4*>(&L[qb + ua0]);
                        o = fmaf(q.x, L[M2b + (ua0 + 0) * 4 + rb], o);
                        o = fmaf(q.y, L[M2b + (ua0 + 1) * 4 + rb], o);
                        o = fmaf(q.z, L[M2b + (ua0 + 2) * 4 + rb], o);
                        o = fmaf(q.w, L[M2b + (ua0 + 3) * 4 + rb], o);
                    }
                    L[OFF_MS5 + g * 64 + cq * 4 + rb] = o;
                }
            }
            __syncthreads();
        }

        // ===== C: write staged data to LDS =====
        if (doP) cvt8(pq, pb0, pb1, &L[OFF_P + sgp * 1024 + k8]);
        if (doQ) cvt8(qq, qb0, qb1,
                      &L[OFF_Q + sgp * 1088 + (k8 >> 6) * 68 + (k8 & 63)]);
        if (hasNext) {
            L[OFF_A2 + tid * 2 + 0] = a2v0;
            L[OFF_A2 + tid * 2 + 1] = a2v1;
        }
        __syncthreads();
    }

    // ---- final chain contraction (rb = 0 after c=5) ----
    if (wid < 2) {
        const int g = wid;
        if (lane < 16) L[OFF_VB + g * 16 + lane] = L[OFF_MS0 + g * 64 + lane * 4];
        for (int rr = 1; rr < 5; ++rr) {
            float a = 0.0f;
            if (lane < 16) {
#pragma unroll
                for (int u = 0; u < 16; ++u)
                    a = fmaf(L[OFF_VB + g * 16 + u],
                             L[OFF_MS + g * 4096 + (rr - 1) * 1024 + lane * 64 +
                               ((u * 4) ^ ((lane & 7) << 2))], a);
            }
            if (lane < 16) L[OFF_VB + g * 16 + lane] = a;
        }
        if (lane == 0 && sBase + g < send) {
            float a = 0.0f;
#pragma unroll
            for (int u = 0; u < 16; ++u)
                a = fmaf(L[OFF_VB + g * 16 + u], L[OFF_MS5 + g * 64 + u * 4], a);
            out[sBase + g] = a;
        }
    }
}

extern "C" void kernel_launch(void* const* d_in, const int* in_sizes, int n_in,
                              void* d_out, int out_size, void* d_ws, size_t ws_size,
                              hipStream_t stream) {
    const int*   x         = (const int*)d_in[0];
    const float* peps      = (const float*)d_in[1];
    const float* base_proj = (const float*)d_in[2];
    const float* W1        = (const float*)d_in[3];
    const float* b1        = (const float*)d_in[4];
    const float* W2        = (const float*)d_in[5];
    const float* b2        = (const float*)d_in[6];
    float*       out       = (float*)d_out;

    const int batch = in_sizes[0] / kNSites;
    const size_t perS = (size_t)kProj * 2;  // bf16 bytes per sample
    int cs = (int)(ws_size / perS);
    if (cs > batch) cs = batch;
    cs &= ~3;
    if (cs < 4) cs = 4;  // requires ws_size >= 409600 B

    for (int s0 = 0; s0 < batch; s0 += cs) {
        int send = s0 + cs; if (send > batch) send = batch;
        int n = send - s0;
        dim3 g1((n + 255) / 256, 200);
        hipLaunchKernelGGL(gen_q, g1, dim3(256), 0, stream,
                           x, W1, b1, W2, b2, (unsigned short*)d_ws, s0, send);
        hipLaunchKernelGGL(tn_con, dim3((n + G - 1) / G), dim3(256), 0, stream,
                           x, peps, base_proj, (const unsigned short*)d_ws, out, s0, send);
    }
}

// Round 11
// 346.727 us; speedup vs baseline: 2.5588x; 1.3598x over previous
//
#include <hip/hip_runtime.h>

// fTN_NNiso: batched PEPS amplitude, MI355X. THREE-PASS:
//  h_prep : h[s][64] = relu(x@W1+b1) fp32 -> ws (once per batch, ~4us)
//  gen_q  : q[s][51200] = h@W2+b2 bf16 -> ws. 64 samples/block, grid 3200
//           (round-9's 256-samp/block grid=800 starved occupancy: 269us vs 184)
//  tn_con : boundary-MPS sweep, G=1 sample/block, 256 threads, LDS 51KB ->
//           3 blocks/CU (round-10's G=2 @77KB = 2 blocks/CU, latency-bound).
//           Phase bodies = round-10 validated (spill-free: WRITE 5.6KB),
//           per-thread acc <= 4 float4, Mold/M2H in shared LDS.
// peps strides (6,6,4,4,4,4,2): r:3072 c:512 l:128 rb:32 a:8 b:2 p:1

constexpr int   kNSites = 36;
constexpr int   kProj   = 51200;
constexpr float kEta    = 0.001f;

__device__ __forceinline__ float4 f4fma(float s, float4 a, float4 c) {
    c.x = fmaf(s, a.x, c.x); c.y = fmaf(s, a.y, c.y);
    c.z = fmaf(s, a.z, c.z); c.w = fmaf(s, a.w, c.w);
    return c;
}
__device__ __forceinline__ unsigned short f2bf(float f) {
    union { float f; unsigned int u; } v; v.f = f;
    unsigned int r = v.u + 0x7FFFu + ((v.u >> 16) & 1u);  // RNE
    return (unsigned short)(r >> 16);
}
__device__ __forceinline__ float bf2f(unsigned int h) {
    union { unsigned int u; float f; } v; v.u = h << 16;
    return v.f;
}
// 4 bf16 (uint2) + base float4 -> vec float4 LDS store. ALL STATIC.
__device__ __forceinline__ void cvt4(const uint2 q, const float4 b, float* dst) {
    float4 o;
    o.x = b.x + kEta * bf2f(q.x & 0xffffu);
    o.y = b.y + kEta * bf2f(q.x >> 16);
    o.z = b.z + kEta * bf2f(q.y & 0xffffu);
    o.w = b.w + kEta * bf2f(q.y >> 16);
    *reinterpret_cast<float4*>(dst) = o;
}

// ===================== PASS 0: h = relu(x@W1+b1) =====================
__global__ __launch_bounds__(256)
void h_prep(const int* __restrict__ x,
            const float* __restrict__ W1,
            const float* __restrict__ b1,
            float* __restrict__ hf,
            int batch)
{
    const int tid = threadIdx.x;
    const int s   = blockIdx.x * 4 + (tid >> 6);   // wave-uniform sample
    const int k   = tid & 63;
    if (s >= batch) return;
    float a = b1[k];
    for (int j = 0; j < kNSites; ++j)
        a = fmaf((float)x[s * kNSites + j], W1[j * 64 + k], a);
    hf[s * 64 + k] = fmaxf(a, 0.0f);
}

// ===================== PASS 1: q = h @ W2 + b2 (bf16) =====================
__global__ __launch_bounds__(256)
void gen_q(const float* __restrict__ hf,
           const float* __restrict__ W2,
           const float* __restrict__ b2,
           unsigned short* __restrict__ qout,
           int s0, int send)
{
    __shared__ float hT[64 * 68];   // [k*68 + sl]
    const int tid   = threadIdx.x;
    const int sbase = s0 + blockIdx.x * 64;
    const int ns    = blockIdx.y;   // 200 strips of 256 cols

    // stage hT[k][sl] from hf[s][k] (transpose)
#pragma unroll
    for (int ii = 0; ii < 4; ++ii) {
        int sl = (tid >> 4) + 16 * ii;
        int sA = sbase + sl; if (sA >= send) sA = send - 1;
        float4 hv = *reinterpret_cast<const float4*>(hf + sA * 64 + (tid & 15) * 4);
        int kb = (tid & 15) * 4;
        hT[(kb + 0) * 68 + sl] = hv.x;
        hT[(kb + 1) * 68 + sl] = hv.y;
        hT[(kb + 2) * 68 + sl] = hv.z;
        hT[(kb + 3) * 68 + sl] = hv.w;
    }
    __syncthreads();

    const int sgrp = tid >> 6;            // wave-uniform 16-sample group
    const int col  = ns * 256 + (tid & 63) * 4;
    float4 acc[16];
#pragma unroll
    for (int i = 0; i < 16; ++i) acc[i] = make_float4(0, 0, 0, 0);
    const float* wp = W2 + col;
#pragma unroll 8
    for (int k = 0; k < 64; ++k) {
        float4 w = *reinterpret_cast<const float4*>(wp + (size_t)k * kProj);
#pragma unroll
        for (int s4 = 0; s4 < 4; ++s4) {
            float4 hv = *reinterpret_cast<const float4*>(&hT[k * 68 + sgrp * 16 + s4 * 4]);
            acc[s4 * 4 + 0] = f4fma(hv.x, w, acc[s4 * 4 + 0]);
            acc[s4 * 4 + 1] = f4fma(hv.y, w, acc[s4 * 4 + 1]);
            acc[s4 * 4 + 2] = f4fma(hv.z, w, acc[s4 * 4 + 2]);
            acc[s4 * 4 + 3] = f4fma(hv.w, w, acc[s4 * 4 + 3]);
        }
    }
    float4 bb = *reinterpret_cast<const float4*>(b2 + col);
#pragma unroll
    for (int i = 0; i < 16; ++i) {
        int sA = sbase + sgrp * 16 + i;
        if (sA < send) {
            ushort4 uv;
            uv.x = f2bf(acc[i].x + bb.x); uv.y = f2bf(acc[i].y + bb.y);
            uv.z = f2bf(acc[i].z + bb.z); uv.w = f2bf(acc[i].w + bb.w);
            *reinterpret_cast<ushort4*>(qout + (size_t)(sA - s0) * kProj + col) = uv;
        }
    }
}

// ===================== PASS 2: contraction sweep, G=1 =====================
// LDS (float offsets)
constexpr int OFF_MS   = 0;       // [r-1][d][(u*4+l)^((d&7)<<2)]      4096
constexpr int OFF_MS0  = 4096;    // [d*4+l]                          64
constexpr int OFF_MS5  = 4160;    // [u*4+l]                          64
constexpr int OFF_P    = 4224;    // [(d*4+b)*16+cc]                  1024
constexpr int OFF_Q    = 5248;    // [cq*68+ua]                       1088
constexpr int OFF_MOLD = 6336;    // [(u*16+lb)*16 + (cc^((u&3)<<2))] 4096
constexpr int OFF_M2H  = 10432;   // [ua*32 + (colh^((ua&7)<<2))]     2048
constexpr int OFF_A2   = 12480;   // [lb*16+a*4+rb]                   256
constexpr int OFF_VB   = 12736;   // [16]                             16
constexpr int LTOT     = 12752;   // 51,008 B -> 3 blocks/CU

__global__ __launch_bounds__(256, 2)
void tn_con(const int* __restrict__ x,
            const float* __restrict__ peps,
            const float* __restrict__ base_proj,
            const unsigned short* __restrict__ qc,
            float* __restrict__ out,
            int s0, int send)
{
    __shared__ __align__(16) float L[LTOT];
    __shared__ int xl[kNSites];

    const int tid  = threadIdx.x;
    const int wid  = tid >> 6;
    const int lane = tid & 63;
    const int sIdx = s0 + blockIdx.x;
    int sAbs = sIdx; if (sAbs >= send) sAbs = send - 1;

    if (tid < kNSites) xl[tid] = x[sAbs * kNSites + tid];
    for (int i = tid; i < 4224; i += 256) L[i] = 0.0f;  // Ms + Ms0 + Ms5
    __syncthreads();

    // ---- init boundary MPS from column 0 ----
    for (int idx = tid; idx < 512; idx += 256) {
        int rr = idx >> 6, u = (idx >> 4) & 3, d = (idx >> 2) & 3, l = idx & 3;
        if (rr >= 6) continue;
        int p = xl[rr * 6];
        if (rr == 0) {
            if (u == 0) L[OFF_MS0 + d * 4 + l] = peps[l * 32 + d * 2 + p];
        } else if (rr == 5) {
            if (d == 0) L[OFF_MS5 + u * 4 + l] = peps[5 * 3072 + l * 32 + u * 8 + p];
        } else {
            L[OFF_MS + (rr - 1) * 1024 + d * 64 + ((u * 4 + l) ^ ((d & 7) << 2))] =
                peps[rr * 3072 + l * 32 + u * 8 + d * 2 + p];
        }
    }

    const unsigned short* qcs = qc + (size_t)(sAbs - s0) * kProj;
    const int k4 = tid * 4;   // 4-float bond chunk per thread

    // ---- prologue: P(bond 0) + A2(site 0: c=1,r=0) ----
    {
        uint2 pq = *reinterpret_cast<const uint2*>(qcs + k4);
        float4 pb = *reinterpret_cast<const float4*>(base_proj + k4);
        cvt4(pq, pb, &L[OFF_P + k4]);
        int lb = tid >> 4, arb = tid & 15;
        int l = lb >> 2, b = lb & 3, a = arb >> 2, rb = arb & 3;
        float v = 0.0f;
        if (a < 1) {
            int p = xl[0 * 6 + 1];
            v = peps[1 * 512 + l * 128 + rb * 32 + a * 8 + b * 2 + p];
        }
        L[OFF_A2 + tid] = v;
    }
    __syncthreads();

    // ---- site loop: s = (c-1)*6 + r ----
    for (int s = 0; s < 30; ++s) {
        const int r = s % 6;

        // ===== A: issue next-site loads into registers =====
        const int s1 = s + 1;
        const bool hasNext = (s1 < 30);
        const int r1 = s1 % 6, c1 = 1 + s1 / 6;
        const bool doP = hasNext && (r1 <= 4);
        const bool doQ = hasNext && (r1 >= 1);
        uint2 pq = make_uint2(0, 0), qq = pq;
        float4 pb = make_float4(0, 0, 0, 0), qb = pb;
        float a2v = 0.0f;
        if (doP) {
            const int go = ((c1 - 1) * 5 + r1) * 2048 + k4;
            pq = *reinterpret_cast<const uint2*>(qcs + go);
            pb = *reinterpret_cast<const float4*>(base_proj + go);
        }
        if (doQ) {
            const int go = ((c1 - 1) * 5 + (r1 - 1)) * 2048 + 1024 + k4;
            qq = *reinterpret_cast<const uint2*>(qcs + go);
            qb = *reinterpret_cast<const float4*>(base_proj + go);
        }
        if (hasNext) {
            const int adim = (r1 == 0) ? 1 : 4;
            const int bdim = (r1 == 5) ? 1 : 4;
            const int rdim = (c1 == 5) ? 1 : 4;
            int lb = tid >> 4, arb = tid & 15;
            int l = lb >> 2, b = lb & 3, a = arb >> 2, rb = arb & 3;
            if (a < adim && b < bdim && rb < rdim) {
                int p = xl[r1 * 6 + c1];
                a2v = peps[r1 * 3072 + c1 * 512 + l * 128 + rb * 32 + a * 8 + b * 2 + p];
            }
        }

        // ===== B: phases =====
        if (r == 0) {
            if (wid == 0) {
                const int cc = lane >> 2, rb = lane & 3;
                float mold0[16];
#pragma unroll
                for (int i = 0; i < 16; ++i) mold0[i] = 0.0f;
#pragma unroll
                for (int d = 0; d < 16; ++d) {
                    float4 ms = *reinterpret_cast<float4*>(&L[OFF_MS0 + d * 4]);
                    float msl[4] = {ms.x, ms.y, ms.z, ms.w};
#pragma unroll
                    for (int b = 0; b < 4; ++b) {
                        float pv = L[OFF_P + (d * 4 + b) * 16 + cc];
#pragma unroll
                        for (int l = 0; l < 4; ++l)
                            mold0[l * 4 + b] = fmaf(msl[l], pv, mold0[l * 4 + b]);
                    }
                }
                float o = 0.0f;
#pragma unroll
                for (int lb = 0; lb < 16; ++lb)
                    o = fmaf(mold0[lb], L[OFF_A2 + lb * 16 + rb], o);
                L[OFF_MS0 + cc * 4 + rb] = o;
            }
            __syncthreads();
        } else if (r < 5) {
            const int msr = OFF_MS + (r - 1) * 1024;
            // ---- p1 (all 256 threads): Mold[u][lb][cc] ----
            {
                const int u = tid >> 4, lb = tid & 15;
                const int l = lb >> 2, b = lb & 3;
                const int pxr = (u & 3) << 2;
                float4 a0 = make_float4(0, 0, 0, 0), a1 = a0, a2 = a0, a3 = a0;
#pragma unroll
                for (int d = 0; d < 16; ++d) {
                    float ms = L[msr + d * 64 + ((u * 4 + l) ^ ((d & 7) << 2))];
                    const int pb2 = OFF_P + (d * 4 + b) * 16;
                    float4 p0 = *reinterpret_cast<float4*>(&L[pb2 + 0]);
                    float4 p1 = *reinterpret_cast<float4*>(&L[pb2 + 4]);
                    float4 p2 = *reinterpret_cast<float4*>(&L[pb2 + 8]);
                    float4 p3 = *reinterpret_cast<float4*>(&L[pb2 + 12]);
                    a0 = f4fma(ms, p0, a0); a1 = f4fma(ms, p1, a1);
                    a2 = f4fma(ms, p2, a2); a3 = f4fma(ms, p3, a3);
                }
                const int mrow = OFF_MOLD + (u * 16 + lb) * 16;
                *reinterpret_cast<float4*>(&L[mrow + (0  ^ pxr)]) = a0;
                *reinterpret_cast<float4*>(&L[mrow + (4  ^ pxr)]) = a1;
                *reinterpret_cast<float4*>(&L[mrow + (8  ^ pxr)]) = a2;
                *reinterpret_cast<float4*>(&L[mrow + (12 ^ pxr)]) = a3;
            }
            __syncthreads();
            // ---- p2/p3 in column halves ----
#pragma unroll
            for (int h = 0; h < 2; ++h) {
                {
                    const int ua = tid >> 2, colq = tid & 3;
                    const int u2 = ua >> 2, a2i = ua & 3;
                    const int pxr = (u2 & 3) << 2;
                    const int cc0 = h * 8 + colq * 2;
                    float4 acc0 = make_float4(0, 0, 0, 0), acc1 = acc0;
#pragma unroll
                    for (int lb = 0; lb < 16; ++lb) {
                        float2 mo = *reinterpret_cast<float2*>(
                            &L[OFF_MOLD + (u2 * 16 + lb) * 16 + (cc0 ^ pxr)]);
                        float4 av = *reinterpret_cast<float4*>(
                            &L[OFF_A2 + lb * 16 + a2i * 4]);
                        acc0 = f4fma(mo.x, av, acc0);
                        acc1 = f4fma(mo.y, av, acc1);
                    }
                    const int m2x = (ua & 7) << 2;
                    *reinterpret_cast<float4*>(
                        &L[OFF_M2H + ua * 32 + (((colq * 2 + 0) * 4) ^ m2x)]) = acc0;
                    *reinterpret_cast<float4*>(
                        &L[OFF_M2H + ua * 32 + (((colq * 2 + 1) * 4) ^ m2x)]) = acc1;
                }
                __syncthreads();
                {
                    const int cq = tid >> 4, cp = tid & 15;
                    const int qb2 = OFF_Q + cq * 68;
                    float ox = 0.0f, oy = 0.0f;
#pragma unroll
                    for (int ua0 = 0; ua0 < 64; ua0 += 4) {
                        float4 q = *reinterpret_cast<float4*>(&L[qb2 + ua0]);
                        float2 m0 = *reinterpret_cast<float2*>(
                            &L[OFF_M2H + (ua0 + 0) * 32 + ((cp * 2) ^ (((ua0 + 0) & 7) << 2))]);
                        float2 m1 = *reinterpret_cast<float2*>(
                            &L[OFF_M2H + (ua0 + 1) * 32 + ((cp * 2) ^ (((ua0 + 1) & 7) << 2))]);
                        float2 m2 = *reinterpret_cast<float2*>(
                            &L[OFF_M2H + (ua0 + 2) * 32 + ((cp * 2) ^ (((ua0 + 2) & 7) << 2))]);
                        float2 m3 = *reinterpret_cast<float2*>(
                            &L[OFF_M2H + (ua0 + 3) * 32 + ((cp * 2) ^ (((ua0 + 3) & 7) << 2))]);
                        ox = fmaf(q.x, m0.x, ox); oy = fmaf(q.x, m0.y, oy);
                        ox = fmaf(q.y, m1.x, ox); oy = fmaf(q.y, m1.y, oy);
                        ox = fmaf(q.z, m2.x, ox); oy = fmaf(q.z, m2.y, oy);
                        ox = fmaf(q.w, m3.x, ox); oy = fmaf(q.w, m3.y, oy);
                    }
                    const int dn = h * 8 + (cp >> 1);
                    const int rb0 = (cp & 1) * 2;
                    float2 o2; o2.x = ox; o2.y = oy;
                    *reinterpret_cast<float2*>(
                        &L[msr + dn * 64 + ((cq * 4 + rb0) ^ ((dn & 7) << 2))]) = o2;
                }
                __syncthreads();
            }
        } else { // r == 5
            if (wid == 0) {
                {
                    const int u5 = lane >> 2, a5 = lane & 3;
                    float4 ms5 = *reinterpret_cast<float4*>(&L[OFF_MS5 + u5 * 4]);
                    float4 o = make_float4(0, 0, 0, 0);
                    o = f4fma(ms5.x, *reinterpret_cast<float4*>(&L[OFF_A2 + 0 * 16 + a5 * 4]), o);
                    o = f4fma(ms5.y, *reinterpret_cast<float4*>(&L[OFF_A2 + 4 * 16 + a5 * 4]), o);
                    o = f4fma(ms5.z, *reinterpret_cast<float4*>(&L[OFF_A2 + 8 * 16 + a5 * 4]), o);
                    o = f4fma(ms5.w, *reinterpret_cast<float4*>(&L[OFF_A2 + 12 * 16 + a5 * 4]), o);
                    *reinterpret_cast<float4*>(&L[OFF_M2H + lane * 4]) = o;
                }
                {
                    const int cq = lane >> 2, rb = lane & 3;
                    const int qb2 = OFF_Q + cq * 68;
                    float o = 0.0f;
#pragma unroll
                    for (int ua0 = 0; ua0 < 64; ua0 += 4) {
                        float4 q = *reinterpret_cast<float4*>(&L[qb2 + ua0]);
                        o = fmaf(q.x, L[OFF_M2H + (ua0 + 0) * 4 + rb], o);
                        o = fmaf(q.y, L[OFF_M2H + (ua0 + 1) * 4 + rb], o);
                        o = fmaf(q.z, L[OFF_M2H + (ua0 + 2) * 4 + rb], o);
                        o = fmaf(q.w, L[OFF_M2H + (ua0 + 3) * 4 + rb], o);
                    }
                    L[OFF_MS5 + cq * 4 + rb] = o;
                }
            }
            __syncthreads();
        }

        // ===== C: write staged data to LDS =====
        if (doP) cvt4(pq, pb, &L[OFF_P + k4]);
        if (doQ) cvt4(qq, qb, &L[OFF_Q + (k4 >> 6) * 68 + (k4 & 63)]);
        if (hasNext) L[OFF_A2 + tid] = a2v;
        __syncthreads();
    }

    // ---- final chain contraction (rb = 0 after c=5) ----
    if (wid == 0) {
        if (lane < 16) L[OFF_VB + lane] = L[OFF_MS0 + lane * 4];
        for (int rr = 1; rr < 5; ++rr) {
            float a = 0.0f;
            if (lane < 16) {
#pragma unroll
                for (int u = 0; u < 16; ++u)
                    a = fmaf(L[OFF_VB + u],
                             L[OFF_MS + (rr - 1) * 1024 + lane * 64 +
                               ((u * 4) ^ ((lane & 7) << 2))], a);
            }
            if (lane < 16) L[OFF_VB + lane] = a;
        }
        if (lane == 0 && sIdx < send) {
            float a = 0.0f;
#pragma unroll
            for (int u = 0; u < 16; ++u)
                a = fmaf(L[OFF_VB + u], L[OFF_MS5 + u * 4], a);
            out[sIdx] = a;
        }
    }
}

extern "C" void kernel_launch(void* const* d_in, const int* in_sizes, int n_in,
                              void* d_out, int out_size, void* d_ws, size_t ws_size,
                              hipStream_t stream) {
    const int*   x         = (const int*)d_in[0];
    const float* peps      = (const float*)d_in[1];
    const float* base_proj = (const float*)d_in[2];
    const float* W1        = (const float*)d_in[3];
    const float* b1        = (const float*)d_in[4];
    const float* W2        = (const float*)d_in[5];
    const float* b2        = (const float*)d_in[6];
    float*       out       = (float*)d_out;

    const int batch = in_sizes[0] / kNSites;
    float*          hf = (float*)d_ws;                                   // 1024*64*4 = 256KB
    unsigned short* q  = (unsigned short*)((char*)d_ws + 262144);

    hipLaunchKernelGGL(h_prep, dim3((batch + 3) / 4), dim3(256), 0, stream,
                       x, W1, b1, hf, batch);

    const size_t perS = (size_t)kProj * 2;  // bf16 bytes per sample
    size_t qbytes = (ws_size > 262144) ? ws_size - 262144 : 0;
    int cs = (int)(qbytes / perS);
    if (cs > batch) cs = batch;
    cs &= ~3;
    if (cs < 4) cs = 4;  // requires ws_size >= 262144 + 409600 B

    for (int s0 = 0; s0 < batch; s0 += cs) {
        int send = s0 + cs; if (send > batch) send = batch;
        int n = send - s0;
        dim3 g1((n + 63) / 64, 200);
        hipLaunchKernelGGL(gen_q, g1, dim3(256), 0, stream,
                           hf, W2, b2, q, s0, send);
        hipLaunchKernelGGL(tn_con, dim3(n), dim3(256), 0, stream,
                           x, peps, base_proj, q, out, s0, send);
    }
}

// Round 12
// 341.528 us; speedup vs baseline: 2.5978x; 1.0152x over previous
//
#include <hip/hip_runtime.h>

// fTN_NNiso: batched PEPS amplitude, MI355X. THREE-PASS:
//  h_prep : h[s][64] = relu(x@W1+b1) fp32 -> ws
//  gen_q  : q[s][51200] = h@W2+b2 bf16 -> ws (64 samples/block, grid 3200)
//  tn_con : boundary-MPS sweep, 1 sample/block, 256 threads, LDS 51KB ->
//           3 blocks/CU. Round-12 change: p2b writes its M2 half into
//           Mold's DEAD column slots (freed by p2a), so p3 runs ONE
//           full-width pass (4 outputs/thread) -> Q rows read once, not
//           twice: p3 lane-traffic 2080 -> ~1090 B/thread (tn_con is
//           LDS-lane-BW bound). Barriers 6 -> 5 per heavy site.
// peps strides (6,6,4,4,4,4,2): r:3072 c:512 l:128 rb:32 a:8 b:2 p:1

constexpr int   kNSites = 36;
constexpr int   kProj   = 51200;
constexpr float kEta    = 0.001f;

__device__ __forceinline__ float4 f4fma(float s, float4 a, float4 c) {
    c.x = fmaf(s, a.x, c.x); c.y = fmaf(s, a.y, c.y);
    c.z = fmaf(s, a.z, c.z); c.w = fmaf(s, a.w, c.w);
    return c;
}
__device__ __forceinline__ unsigned short f2bf(float f) {
    union { float f; unsigned int u; } v; v.f = f;
    unsigned int r = v.u + 0x7FFFu + ((v.u >> 16) & 1u);  // RNE
    return (unsigned short)(r >> 16);
}
__device__ __forceinline__ float bf2f(unsigned int h) {
    union { unsigned int u; float f; } v; v.u = h << 16;
    return v.f;
}
// 4 bf16 (uint2) + base float4 -> vec float4 LDS store. ALL STATIC.
__device__ __forceinline__ void cvt4(const uint2 q, const float4 b, float* dst) {
    float4 o;
    o.x = b.x + kEta * bf2f(q.x & 0xffffu);
    o.y = b.y + kEta * bf2f(q.x >> 16);
    o.z = b.z + kEta * bf2f(q.y & 0xffffu);
    o.w = b.w + kEta * bf2f(q.y >> 16);
    *reinterpret_cast<float4*>(dst) = o;
}

// ===================== PASS 0: h = relu(x@W1+b1) =====================
__global__ __launch_bounds__(256)
void h_prep(const int* __restrict__ x,
            const float* __restrict__ W1,
            const float* __restrict__ b1,
            float* __restrict__ hf,
            int batch)
{
    const int tid = threadIdx.x;
    const int s   = blockIdx.x * 4 + (tid >> 6);
    const int k   = tid & 63;
    if (s >= batch) return;
    float a = b1[k];
    for (int j = 0; j < kNSites; ++j)
        a = fmaf((float)x[s * kNSites + j], W1[j * 64 + k], a);
    hf[s * 64 + k] = fmaxf(a, 0.0f);
}

// ===================== PASS 1: q = h @ W2 + b2 (bf16) =====================
__global__ __launch_bounds__(256)
void gen_q(const float* __restrict__ hf,
           const float* __restrict__ W2,
           const float* __restrict__ b2,
           unsigned short* __restrict__ qout,
           int s0, int send)
{
    __shared__ float hT[64 * 68];   // [k*68 + sl]
    const int tid   = threadIdx.x;
    const int sbase = s0 + blockIdx.x * 64;
    const int ns    = blockIdx.y;   // 200 strips of 256 cols

#pragma unroll
    for (int ii = 0; ii < 4; ++ii) {
        int sl = (tid >> 4) + 16 * ii;
        int sA = sbase + sl; if (sA >= send) sA = send - 1;
        float4 hv = *reinterpret_cast<const float4*>(hf + sA * 64 + (tid & 15) * 4);
        int kb = (tid & 15) * 4;
        hT[(kb + 0) * 68 + sl] = hv.x;
        hT[(kb + 1) * 68 + sl] = hv.y;
        hT[(kb + 2) * 68 + sl] = hv.z;
        hT[(kb + 3) * 68 + sl] = hv.w;
    }
    __syncthreads();

    const int sgrp = tid >> 6;
    const int col  = ns * 256 + (tid & 63) * 4;
    float4 acc[16];
#pragma unroll
    for (int i = 0; i < 16; ++i) acc[i] = make_float4(0, 0, 0, 0);
    const float* wp = W2 + col;
#pragma unroll 8
    for (int k = 0; k < 64; ++k) {
        float4 w = *reinterpret_cast<const float4*>(wp + (size_t)k * kProj);
#pragma unroll
        for (int s4 = 0; s4 < 4; ++s4) {
            float4 hv = *reinterpret_cast<const float4*>(&hT[k * 68 + sgrp * 16 + s4 * 4]);
            acc[s4 * 4 + 0] = f4fma(hv.x, w, acc[s4 * 4 + 0]);
            acc[s4 * 4 + 1] = f4fma(hv.y, w, acc[s4 * 4 + 1]);
            acc[s4 * 4 + 2] = f4fma(hv.z, w, acc[s4 * 4 + 2]);
            acc[s4 * 4 + 3] = f4fma(hv.w, w, acc[s4 * 4 + 3]);
        }
    }
    float4 bb = *reinterpret_cast<const float4*>(b2 + col);
#pragma unroll
    for (int i = 0; i < 16; ++i) {
        int sA = sbase + sgrp * 16 + i;
        if (sA < send) {
            ushort4 uv;
            uv.x = f2bf(acc[i].x + bb.x); uv.y = f2bf(acc[i].y + bb.y);
            uv.z = f2bf(acc[i].z + bb.z); uv.w = f2bf(acc[i].w + bb.w);
            *reinterpret_cast<ushort4*>(qout + (size_t)(sA - s0) * kProj + col) = uv;
        }
    }
}

// ===================== PASS 2: contraction sweep, G=1 =====================
// LDS (float offsets)
constexpr int OFF_MS   = 0;       // [r-1][d][(u*4+l)^((d&7)<<2)]      4096
constexpr int OFF_MS0  = 4096;    // [d*4+l]                          64
constexpr int OFF_MS5  = 4160;    // [u*4+l]                          64
constexpr int OFF_P    = 4224;    // [(d*4+b)*16+cc]                  1024
constexpr int OFF_Q    = 5248;    // [cq*68+ua]                       1088
constexpr int OFF_MOLD = 6336;    // [(u*16+lb)*16 + (cc^((u&3)<<2))] 4096 (cols-A slots reused as M2B)
constexpr int OFF_M2H  = 10432;   // [ua*32 + (colh^((ua&7)<<2))]     2048 (M2 cols 0..31)
constexpr int OFF_A2   = 12480;   // [lb*16+a*4+rb]                   256
constexpr int OFF_VB   = 12736;   // [16]                             16
constexpr int LTOT     = 12752;   // 51,008 B -> 3 blocks/CU

// M2 cols 32..63 live in Mold's dead column-slots (freed after p2a).
// Dead set of physical Mold row mrow is offsets [db, db+8), db = ((mrow>>4)&2)?8:0
// (matches p2a's read-set {0..7}^((u&3)<<2)). Bijective row/offset swizzles
// spread banks; f4/f2 alignment preserved (XOR bits >= access width).
__device__ __forceinline__ int mdead(int ua, int c3) {   // c3 in [0,32)
    int q    = c3 >> 3;
    int mrow = (ua * 4 + q) ^ ((ua >> 1) & 1);
    int db   = ((mrow >> 4) & 2) ? 8 : 0;
    return OFF_MOLD + mrow * 16 + db + ((c3 & 7) ^ ((ua & 1) << 2));
}

__global__ __launch_bounds__(256, 2)
void tn_con(const int* __restrict__ x,
            const float* __restrict__ peps,
            const float* __restrict__ base_proj,
            const unsigned short* __restrict__ qc,
            float* __restrict__ out,
            int s0, int send)
{
    __shared__ __align__(16) float L[LTOT];
    __shared__ int xl[kNSites];

    const int tid  = threadIdx.x;
    const int wid  = tid >> 6;
    const int lane = tid & 63;
    const int sIdx = s0 + blockIdx.x;
    int sAbs = sIdx; if (sAbs >= send) sAbs = send - 1;

    if (tid < kNSites) xl[tid] = x[sAbs * kNSites + tid];
    for (int i = tid; i < 4224; i += 256) L[i] = 0.0f;  // Ms + Ms0 + Ms5
    __syncthreads();

    // ---- init boundary MPS from column 0 ----
    for (int idx = tid; idx < 512; idx += 256) {
        int rr = idx >> 6, u = (idx >> 4) & 3, d = (idx >> 2) & 3, l = idx & 3;
        if (rr >= 6) continue;
        int p = xl[rr * 6];
        if (rr == 0) {
            if (u == 0) L[OFF_MS0 + d * 4 + l] = peps[l * 32 + d * 2 + p];
        } else if (rr == 5) {
            if (d == 0) L[OFF_MS5 + u * 4 + l] = peps[5 * 3072 + l * 32 + u * 8 + p];
        } else {
            L[OFF_MS + (rr - 1) * 1024 + d * 64 + ((u * 4 + l) ^ ((d & 7) << 2))] =
                peps[rr * 3072 + l * 32 + u * 8 + d * 2 + p];
        }
    }

    const unsigned short* qcs = qc + (size_t)(sAbs - s0) * kProj;
    const int k4 = tid * 4;

    // ---- prologue: P(bond 0) + A2(site 0: c=1,r=0) ----
    {
        uint2 pq = *reinterpret_cast<const uint2*>(qcs + k4);
        float4 pb = *reinterpret_cast<const float4*>(base_proj + k4);
        cvt4(pq, pb, &L[OFF_P + k4]);
        int lb = tid >> 4, arb = tid & 15;
        int l = lb >> 2, b = lb & 3, a = arb >> 2, rb = arb & 3;
        float v = 0.0f;
        if (a < 1) {
            int p = xl[0 * 6 + 1];
            v = peps[1 * 512 + l * 128 + rb * 32 + a * 8 + b * 2 + p];
        }
        L[OFF_A2 + tid] = v;
    }
    __syncthreads();

    // ---- site loop: s = (c-1)*6 + r ----
    for (int s = 0; s < 30; ++s) {
        const int r = s % 6;

        // ===== A: issue next-site loads into registers =====
        const int s1 = s + 1;
        const bool hasNext = (s1 < 30);
        const int r1 = s1 % 6, c1 = 1 + s1 / 6;
        const bool doP = hasNext && (r1 <= 4);
        const bool doQ = hasNext && (r1 >= 1);
        uint2 pq = make_uint2(0, 0), qq = pq;
        float4 pb = make_float4(0, 0, 0, 0), qb = pb;
        float a2v = 0.0f;
        if (doP) {
            const int go = ((c1 - 1) * 5 + r1) * 2048 + k4;
            pq = *reinterpret_cast<const uint2*>(qcs + go);
            pb = *reinterpret_cast<const float4*>(base_proj + go);
        }
        if (doQ) {
            const int go = ((c1 - 1) * 5 + (r1 - 1)) * 2048 + 1024 + k4;
            qq = *reinterpret_cast<const uint2*>(qcs + go);
            qb = *reinterpret_cast<const float4*>(base_proj + go);
        }
        if (hasNext) {
            const int adim = (r1 == 0) ? 1 : 4;
            const int bdim = (r1 == 5) ? 1 : 4;
            const int rdim = (c1 == 5) ? 1 : 4;
            int lb = tid >> 4, arb = tid & 15;
            int l = lb >> 2, b = lb & 3, a = arb >> 2, rb = arb & 3;
            if (a < adim && b < bdim && rb < rdim) {
                int p = xl[r1 * 6 + c1];
                a2v = peps[r1 * 3072 + c1 * 512 + l * 128 + rb * 32 + a * 8 + b * 2 + p];
            }
        }

        // ===== B: phases =====
        if (r == 0) {
            if (wid == 0) {
                const int cc = lane >> 2, rb = lane & 3;
                float mold0[16];
#pragma unroll
                for (int i = 0; i < 16; ++i) mold0[i] = 0.0f;
#pragma unroll
                for (int d = 0; d < 16; ++d) {
                    float4 ms = *reinterpret_cast<float4*>(&L[OFF_MS0 + d * 4]);
                    float msl[4] = {ms.x, ms.y, ms.z, ms.w};
#pragma unroll
                    for (int b = 0; b < 4; ++b) {
                        float pv = L[OFF_P + (d * 4 + b) * 16 + cc];
#pragma unroll
                        for (int l = 0; l < 4; ++l)
                            mold0[l * 4 + b] = fmaf(msl[l], pv, mold0[l * 4 + b]);
                    }
                }
                float o = 0.0f;
#pragma unroll
                for (int lb = 0; lb < 16; ++lb)
                    o = fmaf(mold0[lb], L[OFF_A2 + lb * 16 + rb], o);
                L[OFF_MS0 + cc * 4 + rb] = o;
            }
            __syncthreads();
        } else if (r < 5) {
            const int msr = OFF_MS + (r - 1) * 1024;
            // ---- p1: Mold[u][lb][cc] (all 256 threads) ----
            {
                const int u = tid >> 4, lb = tid & 15;
                const int l = lb >> 2, b = lb & 3;
                const int pxr = (u & 3) << 2;
                float4 a0 = make_float4(0, 0, 0, 0), a1 = a0, a2 = a0, a3 = a0;
#pragma unroll
                for (int d = 0; d < 16; ++d) {
                    float ms = L[msr + d * 64 + ((u * 4 + l) ^ ((d & 7) << 2))];
                    const int pb2 = OFF_P + (d * 4 + b) * 16;
                    float4 p0 = *reinterpret_cast<float4*>(&L[pb2 + 0]);
                    float4 p1 = *reinterpret_cast<float4*>(&L[pb2 + 4]);
                    float4 p2 = *reinterpret_cast<float4*>(&L[pb2 + 8]);
                    float4 p3 = *reinterpret_cast<float4*>(&L[pb2 + 12]);
                    a0 = f4fma(ms, p0, a0); a1 = f4fma(ms, p1, a1);
                    a2 = f4fma(ms, p2, a2); a3 = f4fma(ms, p3, a3);
                }
                const int mrow = OFF_MOLD + (u * 16 + lb) * 16;
                *reinterpret_cast<float4*>(&L[mrow + (0  ^ pxr)]) = a0;
                *reinterpret_cast<float4*>(&L[mrow + (4  ^ pxr)]) = a1;
                *reinterpret_cast<float4*>(&L[mrow + (8  ^ pxr)]) = a2;
                *reinterpret_cast<float4*>(&L[mrow + (12 ^ pxr)]) = a3;
            }
            __syncthreads();
            // ---- p2a: M2 cols 0..31 -> M2H ----
            {
                const int ua = tid >> 2, colq = tid & 3;
                const int u2 = ua >> 2, a2i = ua & 3;
                const int pxr = (u2 & 3) << 2;
                const int cc0 = colq * 2;
                float4 acc0 = make_float4(0, 0, 0, 0), acc1 = acc0;
#pragma unroll
                for (int lb = 0; lb < 16; ++lb) {
                    float2 mo = *reinterpret_cast<float2*>(
                        &L[OFF_MOLD + (u2 * 16 + lb) * 16 + (cc0 ^ pxr)]);
                    float4 av = *reinterpret_cast<float4*>(&L[OFF_A2 + lb * 16 + a2i * 4]);
                    acc0 = f4fma(mo.x, av, acc0);
                    acc1 = f4fma(mo.y, av, acc1);
                }
                const int m2x = (ua & 7) << 2;
                *reinterpret_cast<float4*>(
                    &L[OFF_M2H + ua * 32 + (((colq * 2 + 0) * 4) ^ m2x)]) = acc0;
                *reinterpret_cast<float4*>(
                    &L[OFF_M2H + ua * 32 + (((colq * 2 + 1) * 4) ^ m2x)]) = acc1;
            }
            __syncthreads();
            // ---- p2b: M2 cols 32..63 -> Mold dead slots (reads col-B, writes dead col-A) ----
            {
                const int ua = tid >> 2, colq = tid & 3;
                const int u2 = ua >> 2, a2i = ua & 3;
                const int pxr = (u2 & 3) << 2;
                const int cc0 = 8 + colq * 2;
                float4 acc0 = make_float4(0, 0, 0, 0), acc1 = acc0;
#pragma unroll
                for (int lb = 0; lb < 16; ++lb) {
                    float2 mo = *reinterpret_cast<float2*>(
                        &L[OFF_MOLD + (u2 * 16 + lb) * 16 + (cc0 ^ pxr)]);
                    float4 av = *reinterpret_cast<float4*>(&L[OFF_A2 + lb * 16 + a2i * 4]);
                    acc0 = f4fma(mo.x, av, acc0);
                    acc1 = f4fma(mo.y, av, acc1);
                }
                *reinterpret_cast<float4*>(&L[mdead(ua, (colq * 2 + 0) * 4)]) = acc0;
                *reinterpret_cast<float4*>(&L[mdead(ua, (colq * 2 + 1) * 4)]) = acc1;
            }
            __syncthreads();
            // ---- p3 full-width: Ms'[cq][dn][rb] = sum_ua Q[cq][ua]*M2[ua][col] ----
            {
                const int cp  = tid & 31;          // col-pair 0..31
                const int cq0 = (tid >> 5) * 2;    // 0,2,...,14
                const int qb0 = OFF_Q + cq0 * 68;
                const int qb1 = OFF_Q + (cq0 + 1) * 68;
                float ox0 = 0.0f, oy0 = 0.0f, ox1 = 0.0f, oy1 = 0.0f;
#pragma unroll
                for (int ua0 = 0; ua0 < 64; ua0 += 4) {
                    float4 q0 = *reinterpret_cast<float4*>(&L[qb0 + ua0]);
                    float4 q1 = *reinterpret_cast<float4*>(&L[qb1 + ua0]);
                    int a0 = (cp < 16) ? (OFF_M2H + (ua0 + 0) * 32 + ((cp * 2) ^ (((ua0 + 0) & 7) << 2)))
                                       : mdead(ua0 + 0, cp * 2 - 32);
                    int a1 = (cp < 16) ? (OFF_M2H + (ua0 + 1) * 32 + ((cp * 2) ^ (((ua0 + 1) & 7) << 2)))
                                       : mdead(ua0 + 1, cp * 2 - 32);
                    int a2 = (cp < 16) ? (OFF_M2H + (ua0 + 2) * 32 + ((cp * 2) ^ (((ua0 + 2) & 7) << 2)))
                                       : mdead(ua0 + 2, cp * 2 - 32);
                    int a3 = (cp < 16) ? (OFF_M2H + (ua0 + 3) * 32 + ((cp * 2) ^ (((ua0 + 3) & 7) << 2)))
                                       : mdead(ua0 + 3, cp * 2 - 32);
                    float2 m0 = *reinterpret_cast<float2*>(&L[a0]);
                    float2 m1 = *reinterpret_cast<float2*>(&L[a1]);
                    float2 m2 = *reinterpret_cast<float2*>(&L[a2]);
                    float2 m3 = *reinterpret_cast<float2*>(&L[a3]);
                    ox0 = fmaf(q0.x, m0.x, ox0); oy0 = fmaf(q0.x, m0.y, oy0);
                    ox0 = fmaf(q0.y, m1.x, ox0); oy0 = fmaf(q0.y, m1.y, oy0);
                    ox0 = fmaf(q0.z, m2.x, ox0); oy0 = fmaf(q0.z, m2.y, oy0);
                    ox0 = fmaf(q0.w, m3.x, ox0); oy0 = fmaf(q0.w, m3.y, oy0);
                    ox1 = fmaf(q1.x, m0.x, ox1); oy1 = fmaf(q1.x, m0.y, oy1);
                    ox1 = fmaf(q1.y, m1.x, ox1); oy1 = fmaf(q1.y, m1.y, oy1);
                    ox1 = fmaf(q1.z, m2.x, ox1); oy1 = fmaf(q1.z, m2.y, oy1);
                    ox1 = fmaf(q1.w, m3.x, ox1); oy1 = fmaf(q1.w, m3.y, oy1);
                }
                const int dn  = cp >> 1;
                const int rb0 = (cp & 1) * 2;
                const int wsd = (dn & 7) << 2;
                float2 o0; o0.x = ox0; o0.y = oy0;
                float2 o1; o1.x = ox1; o1.y = oy1;
                *reinterpret_cast<float2*>(
                    &L[msr + dn * 64 + ((cq0 * 4 + rb0) ^ wsd)]) = o0;
                *reinterpret_cast<float2*>(
                    &L[msr + dn * 64 + (((cq0 + 1) * 4 + rb0) ^ wsd)]) = o1;
            }
            __syncthreads();
        } else { // r == 5
            if (wid == 0) {
                {
                    const int u5 = lane >> 2, a5 = lane & 3;
                    float4 ms5 = *reinterpret_cast<float4*>(&L[OFF_MS5 + u5 * 4]);
                    float4 o = make_float4(0, 0, 0, 0);
                    o = f4fma(ms5.x, *reinterpret_cast<float4*>(&L[OFF_A2 + 0 * 16 + a5 * 4]), o);
                    o = f4fma(ms5.y, *reinterpret_cast<float4*>(&L[OFF_A2 + 4 * 16 + a5 * 4]), o);
                    o = f4fma(ms5.z, *reinterpret_cast<float4*>(&L[OFF_A2 + 8 * 16 + a5 * 4]), o);
                    o = f4fma(ms5.w, *reinterpret_cast<float4*>(&L[OFF_A2 + 12 * 16 + a5 * 4]), o);
                    *reinterpret_cast<float4*>(&L[OFF_M2H + lane * 4]) = o;
                }
                {
                    const int cq = lane >> 2, rb = lane & 3;
                    const int qb2 = OFF_Q + cq * 68;
                    float o = 0.0f;
#pragma unroll
                    for (int ua0 = 0; ua0 < 64; ua0 += 4) {
                        float4 q = *reinterpret_cast<float4*>(&L[qb2 + ua0]);
                        o = fmaf(q.x, L[OFF_M2H + (ua0 + 0) * 4 + rb], o);
                        o = fmaf(q.y, L[OFF_M2H + (ua0 + 1) * 4 + rb], o);
                        o = fmaf(q.z, L[OFF_M2H + (ua0 + 2) * 4 + rb], o);
                        o = fmaf(q.w, L[OFF_M2H + (ua0 + 3) * 4 + rb], o);
                    }
                    L[OFF_MS5 + cq * 4 + rb] = o;
                }
            }
            __syncthreads();
        }

        // ===== C: write staged data to LDS =====
        if (doP) cvt4(pq, pb, &L[OFF_P + k4]);
        if (doQ) cvt4(qq, qb, &L[OFF_Q + (k4 >> 6) * 68 + (k4 & 63)]);
        if (hasNext) L[OFF_A2 + tid] = a2v;
        __syncthreads();
    }

    // ---- final chain contraction (rb = 0 after c=5) ----
    if (wid == 0) {
        if (lane < 16) L[OFF_VB + lane] = L[OFF_MS0 + lane * 4];
        for (int rr = 1; rr < 5; ++rr) {
            float a = 0.0f;
            if (lane < 16) {
#pragma unroll
                for (int u = 0; u < 16; ++u)
                    a = fmaf(L[OFF_VB + u],
                             L[OFF_MS + (rr - 1) * 1024 + lane * 64 +
                               ((u * 4) ^ ((lane & 7) << 2))], a);
            }
            if (lane < 16) L[OFF_VB + lane] = a;
        }
        if (lane == 0 && sIdx < send) {
            float a = 0.0f;
#pragma unroll
            for (int u = 0; u < 16; ++u)
                a = fmaf(L[OFF_VB + u], L[OFF_MS5 + u * 4], a);
            out[sIdx] = a;
        }
    }
}

extern "C" void kernel_launch(void* const* d_in, const int* in_sizes, int n_in,
                              void* d_out, int out_size, void* d_ws, size_t ws_size,
                              hipStream_t stream) {
    const int*   x         = (const int*)d_in[0];
    const float* peps      = (const float*)d_in[1];
    const float* base_proj = (const float*)d_in[2];
    const float* W1        = (const float*)d_in[3];
    const float* b1        = (const float*)d_in[4];
    const float* W2        = (const float*)d_in[5];
    const float* b2        = (const float*)d_in[6];
    float*       out       = (float*)d_out;

    const int batch = in_sizes[0] / kNSites;
    float*          hf = (float*)d_ws;                                   // 1024*64*4 = 256KB
    unsigned short* q  = (unsigned short*)((char*)d_ws + 262144);

    hipLaunchKernelGGL(h_prep, dim3((batch + 3) / 4), dim3(256), 0, stream,
                       x, W1, b1, hf, batch);

    const size_t perS = (size_t)kProj * 2;  // bf16 bytes per sample
    size_t qbytes = (ws_size > 262144) ? ws_size - 262144 : 0;
    int cs = (int)(qbytes / perS);
    if (cs > batch) cs = batch;
    cs &= ~3;
    if (cs < 4) cs = 4;  // requires ws_size >= 262144 + 409600 B

    for (int s0 = 0; s0 < batch; s0 += cs) {
        int send = s0 + cs; if (send > batch) send = batch;
        int n = send - s0;
        dim3 g1((n + 63) / 64, 200);
        hipLaunchKernelGGL(gen_q, g1, dim3(256), 0, stream,
                           hf, W2, b2, q, s0, send);
        hipLaunchKernelGGL(tn_con, dim3(n), dim3(256), 0, stream,
                           x, peps, base_proj, q, out, s0, send);
    }
}

// Round 13
// 292.070 us; speedup vs baseline: 3.0377x; 1.1693x over previous
//
#include <hip/hip_runtime.h>

// fTN_NNiso: batched PEPS amplitude, MI355X. THREE-PASS:
//  h_prep : h[s][64] = relu(x@W1+b1) fp32 -> ws
//  gen_q  : q[s][51200] = h@W2+b2 bf16 -> ws (64 samples/block, grid 3200)
//  tn_con : boundary-MPS sweep, 1 sample/block, 256 threads, LDS 59KB ->
//           2 blocks/CU. tn_con is LDS-UNIT bound (r12: VALUBusy 27%,
//           compute floor 77us vs 275us). Round-13: halve p1/p2 LDS
//           instruction counts via 2-outputs-per-read (p1: 2 u/thread share
//           P reads; p2: 2 ua/thread share A2+Mold reads), full clean M2
//           (no mdead - r12's dead-slot hack quadrupled conflicts to 36M).
//           Barriers 5 -> 4 per heavy site. Accs <= 4 float4/thread (the
//           round-3 no-spill discipline; r4-9 spilled at acc[16] f4).
// peps strides (6,6,4,4,4,4,2): r:3072 c:512 l:128 rb:32 a:8 b:2 p:1

constexpr int   kNSites = 36;
constexpr int   kProj   = 51200;
constexpr float kEta    = 0.001f;

__device__ __forceinline__ float4 f4fma(float s, float4 a, float4 c) {
    c.x = fmaf(s, a.x, c.x); c.y = fmaf(s, a.y, c.y);
    c.z = fmaf(s, a.z, c.z); c.w = fmaf(s, a.w, c.w);
    return c;
}
__device__ __forceinline__ unsigned short f2bf(float f) {
    union { float f; unsigned int u; } v; v.f = f;
    unsigned int r = v.u + 0x7FFFu + ((v.u >> 16) & 1u);  // RNE
    return (unsigned short)(r >> 16);
}
__device__ __forceinline__ float bf2f(unsigned int h) {
    union { unsigned int u; float f; } v; v.u = h << 16;
    return v.f;
}
// 4 bf16 (uint2) + base float4 -> vec float4 LDS store. ALL STATIC.
__device__ __forceinline__ void cvt4(const uint2 q, const float4 b, float* dst) {
    float4 o;
    o.x = b.x + kEta * bf2f(q.x & 0xffffu);
    o.y = b.y + kEta * bf2f(q.x >> 16);
    o.z = b.z + kEta * bf2f(q.y & 0xffffu);
    o.w = b.w + kEta * bf2f(q.y >> 16);
    *reinterpret_cast<float4*>(dst) = o;
}

// ===================== PASS 0: h = relu(x@W1+b1) =====================
__global__ __launch_bounds__(256)
void h_prep(const int* __restrict__ x,
            const float* __restrict__ W1,
            const float* __restrict__ b1,
            float* __restrict__ hf,
            int batch)
{
    const int tid = threadIdx.x;
    const int s   = blockIdx.x * 4 + (tid >> 6);
    const int k   = tid & 63;
    if (s >= batch) return;
    float a = b1[k];
    for (int j = 0; j < kNSites; ++j)
        a = fmaf((float)x[s * kNSites + j], W1[j * 64 + k], a);
    hf[s * 64 + k] = fmaxf(a, 0.0f);
}

// ===================== PASS 1: q = h @ W2 + b2 (bf16) =====================
__global__ __launch_bounds__(256)
void gen_q(const float* __restrict__ hf,
           const float* __restrict__ W2,
           const float* __restrict__ b2,
           unsigned short* __restrict__ qout,
           int s0, int send)
{
    __shared__ float hT[64 * 68];   // [k*68 + sl]
    const int tid   = threadIdx.x;
    const int sbase = s0 + blockIdx.x * 64;
    const int ns    = blockIdx.y;   // 200 strips of 256 cols

#pragma unroll
    for (int ii = 0; ii < 4; ++ii) {
        int sl = (tid >> 4) + 16 * ii;
        int sA = sbase + sl; if (sA >= send) sA = send - 1;
        float4 hv = *reinterpret_cast<const float4*>(hf + sA * 64 + (tid & 15) * 4);
        int kb = (tid & 15) * 4;
        hT[(kb + 0) * 68 + sl] = hv.x;
        hT[(kb + 1) * 68 + sl] = hv.y;
        hT[(kb + 2) * 68 + sl] = hv.z;
        hT[(kb + 3) * 68 + sl] = hv.w;
    }
    __syncthreads();

    const int sgrp = tid >> 6;
    const int col  = ns * 256 + (tid & 63) * 4;
    float4 acc[16];
#pragma unroll
    for (int i = 0; i < 16; ++i) acc[i] = make_float4(0, 0, 0, 0);
    const float* wp = W2 + col;
#pragma unroll 8
    for (int k = 0; k < 64; ++k) {
        float4 w = *reinterpret_cast<const float4*>(wp + (size_t)k * kProj);
#pragma unroll
        for (int s4 = 0; s4 < 4; ++s4) {
            float4 hv = *reinterpret_cast<const float4*>(&hT[k * 68 + sgrp * 16 + s4 * 4]);
            acc[s4 * 4 + 0] = f4fma(hv.x, w, acc[s4 * 4 + 0]);
            acc[s4 * 4 + 1] = f4fma(hv.y, w, acc[s4 * 4 + 1]);
            acc[s4 * 4 + 2] = f4fma(hv.z, w, acc[s4 * 4 + 2]);
            acc[s4 * 4 + 3] = f4fma(hv.w, w, acc[s4 * 4 + 3]);
        }
    }
    float4 bb = *reinterpret_cast<const float4*>(b2 + col);
#pragma unroll
    for (int i = 0; i < 16; ++i) {
        int sA = sbase + sgrp * 16 + i;
        if (sA < send) {
            ushort4 uv;
            uv.x = f2bf(acc[i].x + bb.x); uv.y = f2bf(acc[i].y + bb.y);
            uv.z = f2bf(acc[i].z + bb.z); uv.w = f2bf(acc[i].w + bb.w);
            *reinterpret_cast<ushort4*>(qout + (size_t)(sA - s0) * kProj + col) = uv;
        }
    }
}

// ===================== PASS 2: contraction sweep, G=1 =====================
// LDS (float offsets)
constexpr int OFF_MS   = 0;       // [r-1][d][(u*4+l)^((d&7)<<2)]       4096
constexpr int OFF_MS0  = 4096;    // [d*4+l]                           64
constexpr int OFF_MS5  = 4160;    // [u*4+l]                           64
constexpr int OFF_P    = 4224;    // [(d*4+b)*16+cc]                   1024
constexpr int OFF_Q    = 5248;    // [cq*68+ua]                        1088
constexpr int OFF_MOLD = 6336;    // [(u*16+lb)*16 + (cc^((u&3)<<2))]  4096 (full)
constexpr int OFF_M2   = 10432;   // [ua*64 + (col^((ua&7)<<2))]       4096 (full, clean)
constexpr int OFF_A2   = 14528;   // [lb*16+a*4+rb]                    256
constexpr int OFF_VB   = 14784;   // [16]                              16
constexpr int LTOT     = 14800;   // 59,200 B -> 2 blocks/CU

__global__ __launch_bounds__(256, 2)
void tn_con(const int* __restrict__ x,
            const float* __restrict__ peps,
            const float* __restrict__ base_proj,
            const unsigned short* __restrict__ qc,
            float* __restrict__ out,
            int s0, int send)
{
    __shared__ __align__(16) float L[LTOT];
    __shared__ int xl[kNSites];

    const int tid  = threadIdx.x;
    const int wid  = tid >> 6;
    const int lane = tid & 63;
    const int sIdx = s0 + blockIdx.x;
    int sAbs = sIdx; if (sAbs >= send) sAbs = send - 1;

    if (tid < kNSites) xl[tid] = x[sAbs * kNSites + tid];
    for (int i = tid; i < 4224; i += 256) L[i] = 0.0f;  // Ms + Ms0 + Ms5
    __syncthreads();

    // ---- init boundary MPS from column 0 ----
    for (int idx = tid; idx < 512; idx += 256) {
        int rr = idx >> 6, u = (idx >> 4) & 3, d = (idx >> 2) & 3, l = idx & 3;
        if (rr >= 6) continue;
        int p = xl[rr * 6];
        if (rr == 0) {
            if (u == 0) L[OFF_MS0 + d * 4 + l] = peps[l * 32 + d * 2 + p];
        } else if (rr == 5) {
            if (d == 0) L[OFF_MS5 + u * 4 + l] = peps[5 * 3072 + l * 32 + u * 8 + p];
        } else {
            L[OFF_MS + (rr - 1) * 1024 + d * 64 + ((u * 4 + l) ^ ((d & 7) << 2))] =
                peps[rr * 3072 + l * 32 + u * 8 + d * 2 + p];
        }
    }

    const unsigned short* qcs = qc + (size_t)(sAbs - s0) * kProj;
    const int k4 = tid * 4;

    // ---- prologue: P(bond 0) + A2(site 0: c=1,r=0) ----
    {
        uint2 pq = *reinterpret_cast<const uint2*>(qcs + k4);
        float4 pb = *reinterpret_cast<const float4*>(base_proj + k4);
        cvt4(pq, pb, &L[OFF_P + k4]);
        int lb = tid >> 4, arb = tid & 15;
        int l = lb >> 2, b = lb & 3, a = arb >> 2, rb = arb & 3;
        float v = 0.0f;
        if (a < 1) {
            int p = xl[0 * 6 + 1];
            v = peps[1 * 512 + l * 128 + rb * 32 + a * 8 + b * 2 + p];
        }
        L[OFF_A2 + tid] = v;
    }
    __syncthreads();

    // ---- site loop: s = (c-1)*6 + r ----
    for (int s = 0; s < 30; ++s) {
        const int r = s % 6;

        // ===== A: issue next-site loads into registers =====
        const int s1 = s + 1;
        const bool hasNext = (s1 < 30);
        const int r1 = s1 % 6, c1 = 1 + s1 / 6;
        const bool doP = hasNext && (r1 <= 4);
        const bool doQ = hasNext && (r1 >= 1);
        uint2 pq = make_uint2(0, 0), qq = pq;
        float4 pb = make_float4(0, 0, 0, 0), qb = pb;
        float a2v = 0.0f;
        if (doP) {
            const int go = ((c1 - 1) * 5 + r1) * 2048 + k4;
            pq = *reinterpret_cast<const uint2*>(qcs + go);
            pb = *reinterpret_cast<const float4*>(base_proj + go);
        }
        if (doQ) {
            const int go = ((c1 - 1) * 5 + (r1 - 1)) * 2048 + 1024 + k4;
            qq = *reinterpret_cast<const uint2*>(qcs + go);
            qb = *reinterpret_cast<const float4*>(base_proj + go);
        }
        if (hasNext) {
            const int adim = (r1 == 0) ? 1 : 4;
            const int bdim = (r1 == 5) ? 1 : 4;
            const int rdim = (c1 == 5) ? 1 : 4;
            int lb = tid >> 4, arb = tid & 15;
            int l = lb >> 2, b = lb & 3, a = arb >> 2, rb = arb & 3;
            if (a < adim && b < bdim && rb < rdim) {
                int p = xl[r1 * 6 + c1];
                a2v = peps[r1 * 3072 + c1 * 512 + l * 128 + rb * 32 + a * 8 + b * 2 + p];
            }
        }

        // ===== B: phases =====
        if (r == 0) {
            if (wid == 0) {
                const int cc = lane >> 2, rb = lane & 3;
                float mold0[16];
#pragma unroll
                for (int i = 0; i < 16; ++i) mold0[i] = 0.0f;
#pragma unroll
                for (int d = 0; d < 16; ++d) {
                    float4 ms = *reinterpret_cast<float4*>(&L[OFF_MS0 + d * 4]);
                    float msl[4] = {ms.x, ms.y, ms.z, ms.w};
#pragma unroll
                    for (int b = 0; b < 4; ++b) {
                        float pv = L[OFF_P + (d * 4 + b) * 16 + cc];
#pragma unroll
                        for (int l = 0; l < 4; ++l)
                            mold0[l * 4 + b] = fmaf(msl[l], pv, mold0[l * 4 + b]);
                    }
                }
                float o = 0.0f;
#pragma unroll
                for (int lb = 0; lb < 16; ++lb)
                    o = fmaf(mold0[lb], L[OFF_A2 + lb * 16 + rb], o);
                L[OFF_MS0 + cc * 4 + rb] = o;
            }
            __syncthreads();
        } else if (r < 5) {
            const int msr = OFF_MS + (r - 1) * 1024;
            // ---- p1: Mold[u][lb][cc], 2 u per thread (shared P reads) ----
            {
                const int up = tid >> 5;           // 0..7, covers u = up, up+8
                const int lb = (tid >> 1) & 15;
                const int chalf = tid & 1;         // cc octet
                const int l = lb >> 2, b = lb & 3;
                const int cbase = chalf * 8;
                float4 m00 = make_float4(0,0,0,0), m01 = m00, m10 = m00, m11 = m00;
#pragma unroll
                for (int d = 0; d < 16; ++d) {
                    const int swd = (d & 7) << 2;
                    float ms0 = L[msr + d * 64 + ((up * 4 + l) ^ swd)];
                    float ms1 = L[msr + d * 64 + (((up + 8) * 4 + l) ^ swd)];
                    const int pbase = OFF_P + (d * 4 + b) * 16 + cbase;
                    float4 p0 = *reinterpret_cast<float4*>(&L[pbase + 0]);
                    float4 p1 = *reinterpret_cast<float4*>(&L[pbase + 4]);
                    m00 = f4fma(ms0, p0, m00); m01 = f4fma(ms0, p1, m01);
                    m10 = f4fma(ms1, p0, m10); m11 = f4fma(ms1, p1, m11);
                }
                const int sw0 = (up & 3) << 2;     // same for up and up+8
                const int r0w = OFF_MOLD + (up * 16 + lb) * 16;
                const int r1w = OFF_MOLD + ((up + 8) * 16 + lb) * 16;
                *reinterpret_cast<float4*>(&L[r0w + ((cbase + 0) ^ sw0)]) = m00;
                *reinterpret_cast<float4*>(&L[r0w + ((cbase + 4) ^ sw0)]) = m01;
                *reinterpret_cast<float4*>(&L[r1w + ((cbase + 0) ^ sw0)]) = m10;
                *reinterpret_cast<float4*>(&L[r1w + ((cbase + 4) ^ sw0)]) = m11;
            }
            __syncthreads();
            // ---- p2: M2[ua][cc*4+rb], 2 ua per thread (shared A2 reads) ----
            {
                const int uap = tid >> 3;          // 0..31, covers ua = uap, uap+32
                const int ccp = tid & 7;           // cc = ccp*2, ccp*2+1
                const int u2 = uap >> 2, a = uap & 3;
                const int sw2 = (u2 & 3) << 2;     // same for u2 and u2+8
                const int cc0 = ccp * 2;
                float4 a00 = make_float4(0,0,0,0), a01 = a00, a10 = a00, a11 = a00;
#pragma unroll
                for (int lb = 0; lb < 16; ++lb) {
                    float2 mo0 = *reinterpret_cast<float2*>(
                        &L[OFF_MOLD + (u2 * 16 + lb) * 16 + (cc0 ^ sw2)]);
                    float2 mo1 = *reinterpret_cast<float2*>(
                        &L[OFF_MOLD + ((u2 + 8) * 16 + lb) * 16 + (cc0 ^ sw2)]);
                    float4 av = *reinterpret_cast<float4*>(&L[OFF_A2 + lb * 16 + a * 4]);
                    a00 = f4fma(mo0.x, av, a00); a01 = f4fma(mo0.y, av, a01);
                    a10 = f4fma(mo1.x, av, a10); a11 = f4fma(mo1.y, av, a11);
                }
                const int swm = (uap & 7) << 2;    // (uap+32)&7 == uap&7
                *reinterpret_cast<float4*>(
                    &L[OFF_M2 + uap * 64 + (((cc0    ) * 4) ^ swm)]) = a00;
                *reinterpret_cast<float4*>(
                    &L[OFF_M2 + uap * 64 + (((cc0 + 1) * 4) ^ swm)]) = a01;
                *reinterpret_cast<float4*>(
                    &L[OFF_M2 + (uap + 32) * 64 + (((cc0    ) * 4) ^ swm)]) = a10;
                *reinterpret_cast<float4*>(
                    &L[OFF_M2 + (uap + 32) * 64 + (((cc0 + 1) * 4) ^ swm)]) = a11;
            }
            __syncthreads();
            // ---- p3: Ms'[cq][dn][rb] = sum_ua Q[cq][ua]*M2[ua][col], 2cq x 2col ----
            {
                const int cq0 = (tid >> 5) * 2;    // 0,2,...,14
                const int cp  = tid & 31;          // col-pair: cols cp*2, cp*2+1
                const int qb0 = OFF_Q + cq0 * 68;
                const int qb1 = qb0 + 68;
                float ox0 = 0.0f, oy0 = 0.0f, ox1 = 0.0f, oy1 = 0.0f;
#pragma unroll
                for (int ua0 = 0; ua0 < 64; ua0 += 4) {
                    float4 q0 = *reinterpret_cast<float4*>(&L[qb0 + ua0]);
                    float4 q1 = *reinterpret_cast<float4*>(&L[qb1 + ua0]);
                    float2 m0 = *reinterpret_cast<float2*>(
                        &L[OFF_M2 + (ua0 + 0) * 64 + ((cp * 2) ^ (((ua0 + 0) & 7) << 2))]);
                    float2 m1 = *reinterpret_cast<float2*>(
                        &L[OFF_M2 + (ua0 + 1) * 64 + ((cp * 2) ^ (((ua0 + 1) & 7) << 2))]);
                    float2 m2 = *reinterpret_cast<float2*>(
                        &L[OFF_M2 + (ua0 + 2) * 64 + ((cp * 2) ^ (((ua0 + 2) & 7) << 2))]);
                    float2 m3 = *reinterpret_cast<float2*>(
                        &L[OFF_M2 + (ua0 + 3) * 64 + ((cp * 2) ^ (((ua0 + 3) & 7) << 2))]);
                    ox0 = fmaf(q0.x, m0.x, ox0); oy0 = fmaf(q0.x, m0.y, oy0);
                    ox0 = fmaf(q0.y, m1.x, ox0); oy0 = fmaf(q0.y, m1.y, oy0);
                    ox0 = fmaf(q0.z, m2.x, ox0); oy0 = fmaf(q0.z, m2.y, oy0);
                    ox0 = fmaf(q0.w, m3.x, ox0); oy0 = fmaf(q0.w, m3.y, oy0);
                    ox1 = fmaf(q1.x, m0.x, ox1); oy1 = fmaf(q1.x, m0.y, oy1);
                    ox1 = fmaf(q1.y, m1.x, ox1); oy1 = fmaf(q1.y, m1.y, oy1);
                    ox1 = fmaf(q1.z, m2.x, ox1); oy1 = fmaf(q1.z, m2.y, oy1);
                    ox1 = fmaf(q1.w, m3.x, ox1); oy1 = fmaf(q1.w, m3.y, oy1);
                }
                const int dn  = cp >> 1;
                const int rb0 = (cp & 1) * 2;
                const int wsd = (dn & 7) << 2;
                float2 o0; o0.x = ox0; o0.y = oy0;
                float2 o1; o1.x = ox1; o1.y = oy1;
                *reinterpret_cast<float2*>(
                    &L[msr + dn * 64 + ((cq0 * 4 + rb0) ^ wsd)]) = o0;
                *reinterpret_cast<float2*>(
                    &L[msr + dn * 64 + (((cq0 + 1) * 4 + rb0) ^ wsd)]) = o1;
            }
            __syncthreads();
        } else { // r == 5
            if (wid == 0) {
                {
                    const int u5 = lane >> 2, a5 = lane & 3;
                    float4 ms5 = *reinterpret_cast<float4*>(&L[OFF_MS5 + u5 * 4]);
                    float4 o = make_float4(0, 0, 0, 0);
                    o = f4fma(ms5.x, *reinterpret_cast<float4*>(&L[OFF_A2 + 0 * 16 + a5 * 4]), o);
                    o = f4fma(ms5.y, *reinterpret_cast<float4*>(&L[OFF_A2 + 4 * 16 + a5 * 4]), o);
                    o = f4fma(ms5.z, *reinterpret_cast<float4*>(&L[OFF_A2 + 8 * 16 + a5 * 4]), o);
                    o = f4fma(ms5.w, *reinterpret_cast<float4*>(&L[OFF_A2 + 12 * 16 + a5 * 4]), o);
                    *reinterpret_cast<float4*>(&L[OFF_M2 + lane * 4]) = o;
                }
                {
                    const int cq = lane >> 2, rb = lane & 3;
                    const int qb2 = OFF_Q + cq * 68;
                    float o = 0.0f;
#pragma unroll
                    for (int ua0 = 0; ua0 < 64; ua0 += 4) {
                        float4 q = *reinterpret_cast<float4*>(&L[qb2 + ua0]);
                        o = fmaf(q.x, L[OFF_M2 + (ua0 + 0) * 4 + rb], o);
                        o = fmaf(q.y, L[OFF_M2 + (ua0 + 1) * 4 + rb], o);
                        o = fmaf(q.z, L[OFF_M2 + (ua0 + 2) * 4 + rb], o);
                        o = fmaf(q.w, L[OFF_M2 + (ua0 + 3) * 4 + rb], o);
                    }
                    L[OFF_MS5 + cq * 4 + rb] = o;
                }
            }
            __syncthreads();
        }

        // ===== C: write staged data to LDS =====
        if (doP) cvt4(pq, pb, &L[OFF_P + k4]);
        if (doQ) cvt4(qq, qb, &L[OFF_Q + (k4 >> 6) * 68 + (k4 & 63)]);
        if (hasNext) L[OFF_A2 + tid] = a2v;
        __syncthreads();
    }

    // ---- final chain contraction (rb = 0 after c=5) ----
    if (wid == 0) {
        if (lane < 16) L[OFF_VB + lane] = L[OFF_MS0 + lane * 4];
        for (int rr = 1; rr < 5; ++rr) {
            float a = 0.0f;
            if (lane < 16) {
#pragma unroll
                for (int u = 0; u < 16; ++u)
                    a = fmaf(L[OFF_VB + u],
                             L[OFF_MS + (rr - 1) * 1024 + lane * 64 +
                               ((u * 4) ^ ((lane & 7) << 2))], a);
            }
            if (lane < 16) L[OFF_VB + lane] = a;
        }
        if (lane == 0 && sIdx < send) {
            float a = 0.0f;
#pragma unroll
            for (int u = 0; u < 16; ++u)
                a = fmaf(L[OFF_VB + u], L[OFF_MS5 + u * 4], a);
            out[sIdx] = a;
        }
    }
}

extern "C" void kernel_launch(void* const* d_in, const int* in_sizes, int n_in,
                              void* d_out, int out_size, void* d_ws, size_t ws_size,
                              hipStream_t stream) {
    const int*   x         = (const int*)d_in[0];
    const float* peps      = (const float*)d_in[1];
    const float* base_proj = (const float*)d_in[2];
    const float* W1        = (const float*)d_in[3];
    const float* b1        = (const float*)d_in[4];
    const float* W2        = (const float*)d_in[5];
    const float* b2        = (const float*)d_in[6];
    float*       out       = (float*)d_out;

    const int batch = in_sizes[0] / kNSites;
    float*          hf = (float*)d_ws;                                   // 1024*64*4 = 256KB
    unsigned short* q  = (unsigned short*)((char*)d_ws + 262144);

    hipLaunchKernelGGL(h_prep, dim3((batch + 3) / 4), dim3(256), 0, stream,
                       x, W1, b1, hf, batch);

    const size_t perS = (size_t)kProj * 2;  // bf16 bytes per sample
    size_t qbytes = (ws_size > 262144) ? ws_size - 262144 : 0;
    int cs = (int)(qbytes / perS);
    if (cs > batch) cs = batch;
    cs &= ~3;
    if (cs < 4) cs = 4;  // requires ws_size >= 262144 + 409600 B

    for (int s0 = 0; s0 < batch; s0 += cs) {
        int send = s0 + cs; if (send > batch) send = batch;
        int n = send - s0;
        dim3 g1((n + 63) / 64, 200);
        hipLaunchKernelGGL(gen_q, g1, dim3(256), 0, stream,
                           hf, W2, b2, q, s0, send);
        hipLaunchKernelGGL(tn_con, dim3(n), dim3(256), 0, stream,
                           x, peps, base_proj, q, out, s0, send);
    }
}

// Round 14
// 289.625 us; speedup vs baseline: 3.0633x; 1.0084x over previous
//
#include <hip/hip_runtime.h>

// fTN_NNiso: batched PEPS amplitude, MI355X. THREE-PASS:
//  h_prep : h[s][64] = relu(x@W1+b1) fp32 -> ws
//  gen_q  : q[s][51200] = h@W2+b2 bf16 -> ws (64 samples/block, grid 3200)
//  tn_con : boundary-MPS sweep, 1 sample/block, 256 threads, LDS 59KB ->
//           2 blocks/CU. LDS-INSTRUCTION bound (r13 model validated:
//           conflicts 36M->5.4M gave 275->223us). Round-14: widen reads --
//           p1 re-tiled (2u x 2l x 4cc)/thread: Ms scalar->f2, P 32->16 f4;
//           p3 re-tiled (2cq x 1cc x 4rb)/thread on 128 threads: M2 f2->f4,
//           Q+M2 instruction counts halved. Accs <= 4 f4/thread (no-spill
//           discipline; r4-9 spilled at acc[16] f4). Layouts unchanged.
// peps strides (6,6,4,4,4,4,2): r:3072 c:512 l:128 rb:32 a:8 b:2 p:1

constexpr int   kNSites = 36;
constexpr int   kProj   = 51200;
constexpr float kEta    = 0.001f;

__device__ __forceinline__ float4 f4fma(float s, float4 a, float4 c) {
    c.x = fmaf(s, a.x, c.x); c.y = fmaf(s, a.y, c.y);
    c.z = fmaf(s, a.z, c.z); c.w = fmaf(s, a.w, c.w);
    return c;
}
__device__ __forceinline__ unsigned short f2bf(float f) {
    union { float f; unsigned int u; } v; v.f = f;
    unsigned int r = v.u + 0x7FFFu + ((v.u >> 16) & 1u);  // RNE
    return (unsigned short)(r >> 16);
}
__device__ __forceinline__ float bf2f(unsigned int h) {
    union { unsigned int u; float f; } v; v.u = h << 16;
    return v.f;
}
// 4 bf16 (uint2) + base float4 -> vec float4 LDS store. ALL STATIC.
__device__ __forceinline__ void cvt4(const uint2 q, const float4 b, float* dst) {
    float4 o;
    o.x = b.x + kEta * bf2f(q.x & 0xffffu);
    o.y = b.y + kEta * bf2f(q.x >> 16);
    o.z = b.z + kEta * bf2f(q.y & 0xffffu);
    o.w = b.w + kEta * bf2f(q.y >> 16);
    *reinterpret_cast<float4*>(dst) = o;
}

// ===================== PASS 0: h = relu(x@W1+b1) =====================
__global__ __launch_bounds__(256)
void h_prep(const int* __restrict__ x,
            const float* __restrict__ W1,
            const float* __restrict__ b1,
            float* __restrict__ hf,
            int batch)
{
    const int tid = threadIdx.x;
    const int s   = blockIdx.x * 4 + (tid >> 6);
    const int k   = tid & 63;
    if (s >= batch) return;
    float a = b1[k];
    for (int j = 0; j < kNSites; ++j)
        a = fmaf((float)x[s * kNSites + j], W1[j * 64 + k], a);
    hf[s * 64 + k] = fmaxf(a, 0.0f);
}

// ===================== PASS 1: q = h @ W2 + b2 (bf16) =====================
__global__ __launch_bounds__(256)
void gen_q(const float* __restrict__ hf,
           const float* __restrict__ W2,
           const float* __restrict__ b2,
           unsigned short* __restrict__ qout,
           int s0, int send)
{
    __shared__ float hT[64 * 68];   // [k*68 + sl]
    const int tid   = threadIdx.x;
    const int sbase = s0 + blockIdx.x * 64;
    const int ns    = blockIdx.y;   // 200 strips of 256 cols

#pragma unroll
    for (int ii = 0; ii < 4; ++ii) {
        int sl = (tid >> 4) + 16 * ii;
        int sA = sbase + sl; if (sA >= send) sA = send - 1;
        float4 hv = *reinterpret_cast<const float4*>(hf + sA * 64 + (tid & 15) * 4);
        int kb = (tid & 15) * 4;
        hT[(kb + 0) * 68 + sl] = hv.x;
        hT[(kb + 1) * 68 + sl] = hv.y;
        hT[(kb + 2) * 68 + sl] = hv.z;
        hT[(kb + 3) * 68 + sl] = hv.w;
    }
    __syncthreads();

    const int sgrp = tid >> 6;
    const int col  = ns * 256 + (tid & 63) * 4;
    float4 acc[16];
#pragma unroll
    for (int i = 0; i < 16; ++i) acc[i] = make_float4(0, 0, 0, 0);
    const float* wp = W2 + col;
#pragma unroll 8
    for (int k = 0; k < 64; ++k) {
        float4 w = *reinterpret_cast<const float4*>(wp + (size_t)k * kProj);
#pragma unroll
        for (int s4 = 0; s4 < 4; ++s4) {
            float4 hv = *reinterpret_cast<const float4*>(&hT[k * 68 + sgrp * 16 + s4 * 4]);
            acc[s4 * 4 + 0] = f4fma(hv.x, w, acc[s4 * 4 + 0]);
            acc[s4 * 4 + 1] = f4fma(hv.y, w, acc[s4 * 4 + 1]);
            acc[s4 * 4 + 2] = f4fma(hv.z, w, acc[s4 * 4 + 2]);
            acc[s4 * 4 + 3] = f4fma(hv.w, w, acc[s4 * 4 + 3]);
        }
    }
    float4 bb = *reinterpret_cast<const float4*>(b2 + col);
#pragma unroll
    for (int i = 0; i < 16; ++i) {
        int sA = sbase + sgrp * 16 + i;
        if (sA < send) {
            ushort4 uv;
            uv.x = f2bf(acc[i].x + bb.x); uv.y = f2bf(acc[i].y + bb.y);
            uv.z = f2bf(acc[i].z + bb.z); uv.w = f2bf(acc[i].w + bb.w);
            *reinterpret_cast<ushort4*>(qout + (size_t)(sA - s0) * kProj + col) = uv;
        }
    }
}

// ===================== PASS 2: contraction sweep, G=1 =====================
// LDS (float offsets)
constexpr int OFF_MS   = 0;       // [r-1][d][(u*4+l)^((d&7)<<2)]       4096
constexpr int OFF_MS0  = 4096;    // [d*4+l]                           64
constexpr int OFF_MS5  = 4160;    // [u*4+l]                           64
constexpr int OFF_P    = 4224;    // [(d*4+b)*16+cc]                   1024
constexpr int OFF_Q    = 5248;    // [cq*68+ua]                        1088
constexpr int OFF_MOLD = 6336;    // [(u*16+lb)*16 + (cc^((u&3)<<2))]  4096 (full)
constexpr int OFF_M2   = 10432;   // [ua*64 + (col^((ua&7)<<2))]       4096 (full, clean)
constexpr int OFF_A2   = 14528;   // [lb*16+a*4+rb]                    256
constexpr int OFF_VB   = 14784;   // [16]                              16
constexpr int LTOT     = 14800;   // 59,200 B -> 2 blocks/CU

__global__ __launch_bounds__(256, 2)
void tn_con(const int* __restrict__ x,
            const float* __restrict__ peps,
            const float* __restrict__ base_proj,
            const unsigned short* __restrict__ qc,
            float* __restrict__ out,
            int s0, int send)
{
    __shared__ __align__(16) float L[LTOT];
    __shared__ int xl[kNSites];

    const int tid  = threadIdx.x;
    const int wid  = tid >> 6;
    const int lane = tid & 63;
    const int sIdx = s0 + blockIdx.x;
    int sAbs = sIdx; if (sAbs >= send) sAbs = send - 1;

    if (tid < kNSites) xl[tid] = x[sAbs * kNSites + tid];
    for (int i = tid; i < 4224; i += 256) L[i] = 0.0f;  // Ms + Ms0 + Ms5
    __syncthreads();

    // ---- init boundary MPS from column 0 ----
    for (int idx = tid; idx < 512; idx += 256) {
        int rr = idx >> 6, u = (idx >> 4) & 3, d = (idx >> 2) & 3, l = idx & 3;
        if (rr >= 6) continue;
        int p = xl[rr * 6];
        if (rr == 0) {
            if (u == 0) L[OFF_MS0 + d * 4 + l] = peps[l * 32 + d * 2 + p];
        } else if (rr == 5) {
            if (d == 0) L[OFF_MS5 + u * 4 + l] = peps[5 * 3072 + l * 32 + u * 8 + p];
        } else {
            L[OFF_MS + (rr - 1) * 1024 + d * 64 + ((u * 4 + l) ^ ((d & 7) << 2))] =
                peps[rr * 3072 + l * 32 + u * 8 + d * 2 + p];
        }
    }

    const unsigned short* qcs = qc + (size_t)(sAbs - s0) * kProj;
    const int k4 = tid * 4;

    // ---- prologue: P(bond 0) + A2(site 0: c=1,r=0) ----
    {
        uint2 pq = *reinterpret_cast<const uint2*>(qcs + k4);
        float4 pb = *reinterpret_cast<const float4*>(base_proj + k4);
        cvt4(pq, pb, &L[OFF_P + k4]);
        int lb = tid >> 4, arb = tid & 15;
        int l = lb >> 2, b = lb & 3, a = arb >> 2, rb = arb & 3;
        float v = 0.0f;
        if (a < 1) {
            int p = xl[0 * 6 + 1];
            v = peps[1 * 512 + l * 128 + rb * 32 + a * 8 + b * 2 + p];
        }
        L[OFF_A2 + tid] = v;
    }
    __syncthreads();

    // ---- site loop: s = (c-1)*6 + r ----
    for (int s = 0; s < 30; ++s) {
        const int r = s % 6;

        // ===== A: issue next-site loads into registers =====
        const int s1 = s + 1;
        const bool hasNext = (s1 < 30);
        const int r1 = s1 % 6, c1 = 1 + s1 / 6;
        const bool doP = hasNext && (r1 <= 4);
        const bool doQ = hasNext && (r1 >= 1);
        uint2 pq = make_uint2(0, 0), qq = pq;
        float4 pb = make_float4(0, 0, 0, 0), qb = pb;
        float a2v = 0.0f;
        if (doP) {
            const int go = ((c1 - 1) * 5 + r1) * 2048 + k4;
            pq = *reinterpret_cast<const uint2*>(qcs + go);
            pb = *reinterpret_cast<const float4*>(base_proj + go);
        }
        if (doQ) {
            const int go = ((c1 - 1) * 5 + (r1 - 1)) * 2048 + 1024 + k4;
            qq = *reinterpret_cast<const uint2*>(qcs + go);
            qb = *reinterpret_cast<const float4*>(base_proj + go);
        }
        if (hasNext) {
            const int adim = (r1 == 0) ? 1 : 4;
            const int bdim = (r1 == 5) ? 1 : 4;
            const int rdim = (c1 == 5) ? 1 : 4;
            int lb = tid >> 4, arb = tid & 15;
            int l = lb >> 2, b = lb & 3, a = arb >> 2, rb = arb & 3;
            if (a < adim && b < bdim && rb < rdim) {
                int p = xl[r1 * 6 + c1];
                a2v = peps[r1 * 3072 + c1 * 512 + l * 128 + rb * 32 + a * 8 + b * 2 + p];
            }
        }

        // ===== B: phases =====
        if (r == 0) {
            if (wid == 0) {
                const int cc = lane >> 2, rb = lane & 3;
                float mold0[16];
#pragma unroll
                for (int i = 0; i < 16; ++i) mold0[i] = 0.0f;
#pragma unroll
                for (int d = 0; d < 16; ++d) {
                    float4 ms = *reinterpret_cast<float4*>(&L[OFF_MS0 + d * 4]);
                    float msl[4] = {ms.x, ms.y, ms.z, ms.w};
#pragma unroll
                    for (int b = 0; b < 4; ++b) {
                        float pv = L[OFF_P + (d * 4 + b) * 16 + cc];
#pragma unroll
                        for (int l = 0; l < 4; ++l)
                            mold0[l * 4 + b] = fmaf(msl[l], pv, mold0[l * 4 + b]);
                    }
                }
                float o = 0.0f;
#pragma unroll
                for (int lb = 0; lb < 16; ++lb)
                    o = fmaf(mold0[lb], L[OFF_A2 + lb * 16 + rb], o);
                L[OFF_MS0 + cc * 4 + rb] = o;
            }
            __syncthreads();
        } else if (r < 5) {
            const int msr = OFF_MS + (r - 1) * 1024;
            // ---- p1: Mold[u][lb][cc], (2u x 2l x 4cc)/thread: f2 Ms, 1 f4 P/d ----
            {
                const int up  = tid >> 5;          // 0..7 -> u = up, up+8
                const int lp  = (tid >> 4) & 1;    // l = 2lp, 2lp+1
                const int b   = (tid >> 2) & 3;
                const int ccb = (tid & 3) * 4;     // cc quarter
                float4 m00 = make_float4(0,0,0,0), m01 = m00, m10 = m00, m11 = m00;
#pragma unroll
                for (int d = 0; d < 16; ++d) {
                    const int swd = (d & 7) << 2;
                    float2 ms0 = *reinterpret_cast<float2*>(
                        &L[msr + d * 64 + ((up * 4 + 2 * lp) ^ swd)]);
                    float2 ms1 = *reinterpret_cast<float2*>(
                        &L[msr + d * 64 + (((up + 8) * 4 + 2 * lp) ^ swd)]);
                    float4 p = *reinterpret_cast<float4*>(&L[OFF_P + (d * 4 + b) * 16 + ccb]);
                    m00 = f4fma(ms0.x, p, m00); m01 = f4fma(ms0.y, p, m01);
                    m10 = f4fma(ms1.x, p, m10); m11 = f4fma(ms1.y, p, m11);
                }
                const int sw0 = (up & 3) << 2;     // same for up and up+8
                const int off = ccb ^ sw0;
                *reinterpret_cast<float4*>(
                    &L[OFF_MOLD + (up * 16 + (2 * lp) * 4 + b) * 16 + off]) = m00;
                *reinterpret_cast<float4*>(
                    &L[OFF_MOLD + (up * 16 + (2 * lp + 1) * 4 + b) * 16 + off]) = m01;
                *reinterpret_cast<float4*>(
                    &L[OFF_MOLD + ((up + 8) * 16 + (2 * lp) * 4 + b) * 16 + off]) = m10;
                *reinterpret_cast<float4*>(
                    &L[OFF_MOLD + ((up + 8) * 16 + (2 * lp + 1) * 4 + b) * 16 + off]) = m11;
            }
            __syncthreads();
            // ---- p2: M2[ua][cc*4+rb], 2 ua per thread (shared A2 reads) ----
            {
                const int uap = tid >> 3;          // 0..31, covers ua = uap, uap+32
                const int ccp = tid & 7;           // cc = ccp*2, ccp*2+1
                const int u2 = uap >> 2, a = uap & 3;
                const int sw2 = (u2 & 3) << 2;     // same for u2 and u2+8
                const int cc0 = ccp * 2;
                float4 a00 = make_float4(0,0,0,0), a01 = a00, a10 = a00, a11 = a00;
#pragma unroll
                for (int lb = 0; lb < 16; ++lb) {
                    float2 mo0 = *reinterpret_cast<float2*>(
                        &L[OFF_MOLD + (u2 * 16 + lb) * 16 + (cc0 ^ sw2)]);
                    float2 mo1 = *reinterpret_cast<float2*>(
                        &L[OFF_MOLD + ((u2 + 8) * 16 + lb) * 16 + (cc0 ^ sw2)]);
                    float4 av = *reinterpret_cast<float4*>(&L[OFF_A2 + lb * 16 + a * 4]);
                    a00 = f4fma(mo0.x, av, a00); a01 = f4fma(mo0.y, av, a01);
                    a10 = f4fma(mo1.x, av, a10); a11 = f4fma(mo1.y, av, a11);
                }
                const int swm = (uap & 7) << 2;    // (uap+32)&7 == uap&7
                *reinterpret_cast<float4*>(
                    &L[OFF_M2 + uap * 64 + (((cc0    ) * 4) ^ swm)]) = a00;
                *reinterpret_cast<float4*>(
                    &L[OFF_M2 + uap * 64 + (((cc0 + 1) * 4) ^ swm)]) = a01;
                *reinterpret_cast<float4*>(
                    &L[OFF_M2 + (uap + 32) * 64 + (((cc0    ) * 4) ^ swm)]) = a10;
                *reinterpret_cast<float4*>(
                    &L[OFF_M2 + (uap + 32) * 64 + (((cc0 + 1) * 4) ^ swm)]) = a11;
            }
            __syncthreads();
            // ---- p3: Ms'[cq][dn=cc][rb] = sum_ua Q[cq][ua]*M2[ua][cc*4+rb]
            //      (2cq x 1cc x 4rb)/thread on 128 threads, all-f4 reads ----
            if (tid < 128) {
                const int cq0 = (tid >> 4) * 2;    // 0,2,...,14
                const int cc  = tid & 15;
                const int qb0 = OFF_Q + cq0 * 68;
                const int qb1 = qb0 + 68;
                const int cb  = cc * 4;
                float4 o0 = make_float4(0, 0, 0, 0), o1 = o0;
#pragma unroll
                for (int ua0 = 0; ua0 < 64; ua0 += 4) {
                    float4 q0 = *reinterpret_cast<float4*>(&L[qb0 + ua0]);
                    float4 q1 = *reinterpret_cast<float4*>(&L[qb1 + ua0]);
                    float4 m0 = *reinterpret_cast<float4*>(
                        &L[OFF_M2 + (ua0 + 0) * 64 + (cb ^ (((ua0 + 0) & 7) << 2))]);
                    float4 m1 = *reinterpret_cast<float4*>(
                        &L[OFF_M2 + (ua0 + 1) * 64 + (cb ^ (((ua0 + 1) & 7) << 2))]);
                    float4 m2 = *reinterpret_cast<float4*>(
                        &L[OFF_M2 + (ua0 + 2) * 64 + (cb ^ (((ua0 + 2) & 7) << 2))]);
                    float4 m3 = *reinterpret_cast<float4*>(
                        &L[OFF_M2 + (ua0 + 3) * 64 + (cb ^ (((ua0 + 3) & 7) << 2))]);
                    o0 = f4fma(q0.x, m0, o0); o0 = f4fma(q0.y, m1, o0);
                    o0 = f4fma(q0.z, m2, o0); o0 = f4fma(q0.w, m3, o0);
                    o1 = f4fma(q1.x, m0, o1); o1 = f4fma(q1.y, m1, o1);
                    o1 = f4fma(q1.z, m2, o1); o1 = f4fma(q1.w, m3, o1);
                }
                const int wsd = (cc & 7) << 2;
                *reinterpret_cast<float4*>(&L[msr + cc * 64 + ((cq0 * 4) ^ wsd)]) = o0;
                *reinterpret_cast<float4*>(&L[msr + cc * 64 + (((cq0 + 1) * 4) ^ wsd)]) = o1;
            }
            __syncthreads();
        } else { // r == 5
            if (wid == 0) {
                {
                    const int u5 = lane >> 2, a5 = lane & 3;
                    float4 ms5 = *reinterpret_cast<float4*>(&L[OFF_MS5 + u5 * 4]);
                    float4 o = make_float4(0, 0, 0, 0);
                    o = f4fma(ms5.x, *reinterpret_cast<float4*>(&L[OFF_A2 + 0 * 16 + a5 * 4]), o);
                    o = f4fma(ms5.y, *reinterpret_cast<float4*>(&L[OFF_A2 + 4 * 16 + a5 * 4]), o);
                    o = f4fma(ms5.z, *reinterpret_cast<float4*>(&L[OFF_A2 + 8 * 16 + a5 * 4]), o);
                    o = f4fma(ms5.w, *reinterpret_cast<float4*>(&L[OFF_A2 + 12 * 16 + a5 * 4]), o);
                    *reinterpret_cast<float4*>(&L[OFF_M2 + lane * 4]) = o;
                }
                {
                    const int cq = lane >> 2, rb = lane & 3;
                    const int qb2 = OFF_Q + cq * 68;
                    float o = 0.0f;
#pragma unroll
                    for (int ua0 = 0; ua0 < 64; ua0 += 4) {
                        float4 q = *reinterpret_cast<float4*>(&L[qb2 + ua0]);
                        o = fmaf(q.x, L[OFF_M2 + (ua0 + 0) * 4 + rb], o);
                        o = fmaf(q.y, L[OFF_M2 + (ua0 + 1) * 4 + rb], o);
                        o = fmaf(q.z, L[OFF_M2 + (ua0 + 2) * 4 + rb], o);
                        o = fmaf(q.w, L[OFF_M2 + (ua0 + 3) * 4 + rb], o);
                    }
                    L[OFF_MS5 + cq * 4 + rb] = o;
                }
            }
            __syncthreads();
        }

        // ===== C: write staged data to LDS =====
        if (doP) cvt4(pq, pb, &L[OFF_P + k4]);
        if (doQ) cvt4(qq, qb, &L[OFF_Q + (k4 >> 6) * 68 + (k4 & 63)]);
        if (hasNext) L[OFF_A2 + tid] = a2v;
        __syncthreads();
    }

    // ---- final chain contraction (rb = 0 after c=5) ----
    if (wid == 0) {
        if (lane < 16) L[OFF_VB + lane] = L[OFF_MS0 + lane * 4];
        for (int rr = 1; rr < 5; ++rr) {
            float a = 0.0f;
            if (lane < 16) {
#pragma unroll
                for (int u = 0; u < 16; ++u)
                    a = fmaf(L[OFF_VB + u],
                             L[OFF_MS + (rr - 1) * 1024 + lane * 64 +
                               ((u * 4) ^ ((lane & 7) << 2))], a);
            }
            if (lane < 16) L[OFF_VB + lane] = a;
        }
        if (lane == 0 && sIdx < send) {
            float a = 0.0f;
#pragma unroll
            for (int u = 0; u < 16; ++u)
                a = fmaf(L[OFF_VB + u], L[OFF_MS5 + u * 4], a);
            out[sIdx] = a;
        }
    }
}

extern "C" void kernel_launch(void* const* d_in, const int* in_sizes, int n_in,
                              void* d_out, int out_size, void* d_ws, size_t ws_size,
                              hipStream_t stream) {
    const int*   x         = (const int*)d_in[0];
    const float* peps      = (const float*)d_in[1];
    const float* base_proj = (const float*)d_in[2];
    const float* W1        = (const float*)d_in[3];
    const float* b1        = (const float*)d_in[4];
    const float* W2        = (const float*)d_in[5];
    const float* b2        = (const float*)d_in[6];
    float*       out       = (float*)d_out;

    const int batch = in_sizes[0] / kNSites;
    float*          hf = (float*)d_ws;                                   // 1024*64*4 = 256KB
    unsigned short* q  = (unsigned short*)((char*)d_ws + 262144);

    hipLaunchKernelGGL(h_prep, dim3((batch + 3) / 4), dim3(256), 0, stream,
                       x, W1, b1, hf, batch);

    const size_t perS = (size_t)kProj * 2;  // bf16 bytes per sample
    size_t qbytes = (ws_size > 262144) ? ws_size - 262144 : 0;
    int cs = (int)(qbytes / perS);
    if (cs > batch) cs = batch;
    cs &= ~3;
    if (cs < 4) cs = 4;  // requires ws_size >= 262144 + 409600 B

    for (int s0 = 0; s0 < batch; s0 += cs) {
        int send = s0 + cs; if (send > batch) send = batch;
        int n = send - s0;
        dim3 g1((n + 63) / 64, 200);
        hipLaunchKernelGGL(gen_q, g1, dim3(256), 0, stream,
                           hf, W2, b2, q, s0, send);
        hipLaunchKernelGGL(tn_con, dim3(n), dim3(256), 0, stream,
                           x, peps, base_proj, q, out, s0, send);
    }
}